// Round 8
// baseline (601.890 us; speedup 1.0000x reference)
//
#include <hip/hip_runtime.h>

#define NN     10000
#define DI     128
#define DO     256
#define KNB    32
#define NSRC   33      // 32 neighbors + self
#define RB     16
#define NP2    10240
#define NTILE  640     // NP2/16 col tiles
#define ATILE  626     // row tiles (covers 10016 = 313*32 rows, pad zeroed)
#define CAP    1024    // per-row candidate capacity
#define NEG    0.2f

typedef __attribute__((ext_vector_type(8))) short bf16x8;
typedef __attribute__((ext_vector_type(4))) float f32x4;

// monotone map f32 -> u32 preserving < order (handles negatives)
__device__ __forceinline__ unsigned fkey(float f) {
    unsigned u = __float_as_uint(f);
    return (u & 0x80000000u) ? ~u : (u | 0x80000000u);
}
__device__ __forceinline__ unsigned short bf16rne(float f) {
    unsigned u = __float_as_uint(f);
    unsigned r = u + 0x7FFFu + ((u >> 16) & 1u);
    return (unsigned short)(r >> 16);
}

// Fused prep: stage 16 rows of x, emit A-fragments (hi+lo planes), B-fragments
// (hi plane only; A-side split carries the precision), f64/f32 squared norms.
// Fragment layout (MFMA 16x16x32 bf16): elem(k, idx):
//   tile=idx>>4, lane=((k>>3)&3)*16+(idx&15), ks=k>>5, j=k&7
//   B: Bh[((tile*4+ks)*64+lane)*8+j]; A: same + plane stride 512 (hi,lo)
__global__ __launch_bounds__(256) void prep_k(const float* __restrict__ x,
    unsigned short* __restrict__ aF, unsigned short* __restrict__ Bh,
    double* __restrict__ sq64, float* __restrict__ sq32)
{
    __shared__ float xs[16][132];   // +4 pad: conflict-free strided reads
    const int t = threadIdx.x;
    const int tile = blockIdx.x;
    const int i0 = tile * 16;
#pragma unroll
    for (int q = 0; q < 2; ++q) {
        const int idx = t + 256 * q;
        const int r = idx >> 5, c4 = idx & 31;
        float4 v = make_float4(0.f, 0.f, 0.f, 0.f);
        if (i0 + r < NN) v = *(const float4*)(x + (size_t)(i0 + r) * DI + c4 * 4);
        *(float4*)&xs[r][c4 * 4] = v;
    }
    __syncthreads();
    const int ks = t >> 6, flane = t & 63;
    const int srow = flane & 15;
    const int kb = ks * 32 + ((flane >> 4) & 3) * 8;
    unsigned hi2[4], lo2[4];
#pragma unroll
    for (int j = 0; j < 4; ++j) {
        const float v0 = xs[srow][kb + 2 * j], v1 = xs[srow][kb + 2 * j + 1];
        const unsigned short h0 = bf16rne(v0), h1 = bf16rne(v1);
        const unsigned short l0 = bf16rne(v0 - __uint_as_float((unsigned)h0 << 16));
        const unsigned short l1 = bf16rne(v1 - __uint_as_float((unsigned)h1 << 16));
        hi2[j] = (unsigned)h0 | ((unsigned)h1 << 16);
        lo2[j] = (unsigned)l0 | ((unsigned)l1 << 16);
    }
    *(uint4*)(Bh + ((size_t)(tile * 4 + ks) * 64 + flane) * 8) =
        make_uint4(hi2[0], hi2[1], hi2[2], hi2[3]);
    if (tile < ATILE) {
        unsigned short* pa = aF + (((size_t)(tile * 4 + ks) * 2) * 64 + flane) * 8;
        *(uint4*)pa         = make_uint4(hi2[0], hi2[1], hi2[2], hi2[3]);
        *(uint4*)(pa + 512) = make_uint4(lo2[0], lo2[1], lo2[2], lo2[3]);
    }
    const int row = t >> 4, sub = t & 15;
    double s = 0.0;
#pragma unroll
    for (int q = 0; q < 8; ++q) {
        const float v = xs[row][sub * 8 + q];
        s = fma((double)v, (double)v, s);
    }
#pragma unroll
    for (int off = 8; off >= 1; off >>= 1) s += __shfl_xor(s, off);
    if (sub == 0) {
        const int gi = i0 + row;
        sq32[gi] = (gi < NN) ? (float)s : 0.f;
        if (gi < ATILE * 16) sq64[gi] = s;
    }
}

// Per-row threshold from the chunk-0 sample: 16th-smallest u16 key of the
// row's 512 distances -> Trow = raw-u32 compare bound. Same MFMA chain and
// dd expression as knn_emit_k => bitwise-consistent selection.
__global__ __launch_bounds__(256) void thresh_k(
    const unsigned short* __restrict__ aF, const unsigned short* __restrict__ Bh,
    const float* __restrict__ sq32, unsigned* __restrict__ Trow)
{
    __shared__ unsigned short dist16[RB][512];
    const int rt = blockIdx.x;
    const int r0 = rt * 16;
    const int t = threadIdx.x;
    const int wid = t >> 6, lane = t & 63;
    const int wbase = wid * 128, l15 = lane & 15, rgrp = (lane >> 4) * 4;

    bf16x8 ah[4], al[4];
#pragma unroll
    for (int ks = 0; ks < 4; ++ks) {
        const unsigned short* pa = aF + (((size_t)(rt * 4 + ks) * 2) * 64 + lane) * 8;
        ah[ks] = *(const bf16x8*)pa;
        al[ks] = *(const bf16x8*)(pa + 512);
    }
    float sqiv[4];
#pragma unroll
    for (int rg = 0; rg < 4; ++rg) sqiv[rg] = sq32[r0 + rgrp + rg];

#pragma unroll 1
    for (int ct = 0; ct < 8; ++ct) {
        const int ctg = wid * 8 + ct;
        bf16x8 bh[4];
#pragma unroll
        for (int ks = 0; ks < 4; ++ks)
            bh[ks] = *(const bf16x8*)(Bh + ((size_t)(ctg * 4 + ks) * 64 + lane) * 8);
        f32x4 acc = {0.f, 0.f, 0.f, 0.f};
#pragma unroll
        for (int ks = 0; ks < 4; ++ks) {
            acc = __builtin_amdgcn_mfma_f32_16x16x32_bf16(ah[ks], bh[ks], acc, 0, 0, 0);
            acc = __builtin_amdgcn_mfma_f32_16x16x32_bf16(al[ks], bh[ks], acc, 0, 0, 0);
        }
        const int col = wbase + ct * 16 + l15;
        const float sqj = sq32[col];
#pragma unroll
        for (int rg = 0; rg < 4; ++rg) {
            const int row = r0 + rgrp + rg;
            const float dd = __builtin_fmaf(-2.f, acc[rg], sqiv[rg] + sqj);
            unsigned k16 = (__float_as_uint(dd) >> 16) | 0x8000u;
            if (col >= NN || col == row) k16 = 0xFFFFu;
            dist16[rgrp + rg][col] = (unsigned short)k16;
        }
    }
    __syncthreads();

#pragma unroll 1
    for (int rr = 0; rr < 4; ++rr) {
        const int r = wid * 4 + rr;
        unsigned kk[8];
#pragma unroll
        for (int u = 0; u < 8; ++u) kk[u] = dist16[r][lane + 64 * u];
        unsigned lo = 0, hi = 0xFFFFu;
#pragma unroll 1
        for (int it = 0; it < 16; ++it) {
            const unsigned mid = (lo + hi) >> 1;
            int cnt2 = 0;
#pragma unroll
            for (int u = 0; u < 8; ++u)
                cnt2 += (int)__popcll(__ballot(kk[u] <= mid));
            if (cnt2 >= 16) hi = mid; else lo = mid;
        }
        // raw-bits bound: raw(dd) <= TU  <=>  key16(dd) <= T16  (dd >= 0)
        if (lane == 0) Trow[r0 + r] = ((hi & 0x7FFFu) << 16) | 0xFFFFu;
    }
}

// Main pass: 32 rows x 512 cols per block, 2-MFMA A-split distances, no LDS,
// no per-chunk selection: compare raw bits vs Trow and ballot-append matches.
__global__ __launch_bounds__(256) void knn_emit_k(
    const unsigned short* __restrict__ aF, const unsigned short* __restrict__ Bh,
    const float* __restrict__ sq32, const unsigned* __restrict__ Trow,
    unsigned* __restrict__ cnt, unsigned* __restrict__ cand)
{
    const int r0 = blockIdx.x * 32;
    const int cbase = blockIdx.y * 512;
    const int t = threadIdx.x;
    const int wid = t >> 6, lane = t & 63;
    const int wbase = wid * 128, l15 = lane & 15, rgrp = (lane >> 4) * 4;

    bf16x8 ah[2][4], al[2][4];
#pragma unroll
    for (int rt2 = 0; rt2 < 2; ++rt2)
#pragma unroll
        for (int ks = 0; ks < 4; ++ks) {
            const int rt = (r0 >> 4) + rt2;
            const unsigned short* pa = aF + (((size_t)(rt * 4 + ks) * 2) * 64 + lane) * 8;
            ah[rt2][ks] = *(const bf16x8*)pa;
            al[rt2][ks] = *(const bf16x8*)(pa + 512);
        }
    float sqiv[2][4];
    unsigned TUv[2][4];
#pragma unroll
    for (int rt2 = 0; rt2 < 2; ++rt2)
#pragma unroll
        for (int rg = 0; rg < 4; ++rg) {
            const int row = r0 + rt2 * 16 + rgrp + rg;
            sqiv[rt2][rg] = sq32[row];
            TUv[rt2][rg] = Trow[row];
        }

#define EMIT(ACC, RT2) { \
    _Pragma("unroll") \
    for (int rg = 0; rg < 4; ++rg) { \
        const int row = r0 + (RT2) * 16 + rgrp + rg; \
        const float dd = __builtin_fmaf(-2.f, (ACC)[rg], sqiv[RT2][rg] + sqj); \
        const unsigned raw = __float_as_uint(dd); \
        const bool pass = (raw <= TUv[RT2][rg]) && (col < NN) && (col != row) && (row < NN); \
        const unsigned long long b = __ballot(pass); \
        const unsigned sub16 = (unsigned)((b >> (lane & 48)) & 0xFFFFull); \
        if (sub16) { \
            const int lead = (lane & 48) + (__ffs(sub16) - 1); \
            unsigned base = 0; \
            if (lane == lead) base = atomicAdd(&cnt[row], (unsigned)__popc(sub16)); \
            base = __shfl(base, lead); \
            if (pass) { \
                const unsigned slot = base + (unsigned)__popc(sub16 & ((1u << l15) - 1)); \
                if (slot < CAP) \
                    cand[(size_t)row * CAP + slot] = \
                        (((raw >> 16) | 0x8000u) << 16) | (unsigned)col; \
            } \
        } \
    } }

#pragma unroll 1
    for (int ct = 0; ct < 8; ++ct) {
        const int ctg = (cbase >> 4) + wid * 8 + ct;
        bf16x8 bh[4];
#pragma unroll
        for (int ks = 0; ks < 4; ++ks)
            bh[ks] = *(const bf16x8*)(Bh + ((size_t)(ctg * 4 + ks) * 64 + lane) * 8);
        f32x4 a0 = {0.f, 0.f, 0.f, 0.f}, a1 = {0.f, 0.f, 0.f, 0.f};
#pragma unroll
        for (int ks = 0; ks < 4; ++ks) {
            a0 = __builtin_amdgcn_mfma_f32_16x16x32_bf16(ah[0][ks], bh[ks], a0, 0, 0, 0);
            a0 = __builtin_amdgcn_mfma_f32_16x16x32_bf16(al[0][ks], bh[ks], a0, 0, 0, 0);
            a1 = __builtin_amdgcn_mfma_f32_16x16x32_bf16(ah[1][ks], bh[ks], a1, 0, 0, 0);
            a1 = __builtin_amdgcn_mfma_f32_16x16x32_bf16(al[1][ks], bh[ks], a1, 0, 0, 0);
        }
        const int col = cbase + wbase + ct * 16 + l15;
        const float sqj = sq32[col];
        EMIT(a0, 0)
        EMIT(a1, 1)
    }
#undef EMIT
}

// Per row: top-64 of <=CAP candidates by packed (key16,col), exact f64 rerank,
// emit final top-32 in (f32-dist, col) order. One wave per row.
__global__ void rerank_select_k(const float* __restrict__ x,
    const double* __restrict__ sq64, const unsigned* __restrict__ cand,
    const unsigned* __restrict__ cnt, int* __restrict__ nbr)
{
    __shared__ unsigned cbuf[64];
    const int i = blockIdx.x;
    const int lane = threadIdx.x;   // 64
    unsigned n = cnt[i]; if (n > CAP) n = CAP;
    unsigned kk[CAP / 64];
#pragma unroll
    for (int u = 0; u < CAP / 64; ++u) {
        const unsigned idx = (unsigned)lane + 64u * u;
        kk[u] = (idx < n) ? cand[(size_t)i * CAP + idx] : 0xFFFFFFFFu;
    }
    unsigned lo = 0, hi = 0xFFFFFFFFu;
#pragma unroll 1
    for (int it = 0; it < 32; ++it) {
        const unsigned mid = lo + ((hi - lo) >> 1);
        int c2 = 0;
#pragma unroll
        for (int u = 0; u < CAP / 64; ++u)
            c2 += (int)__popcll(__ballot(kk[u] <= mid));
        if (c2 >= 64) hi = mid; else lo = mid;
    }
    const unsigned T = hi;
    const unsigned long long lml = (1ull << lane) - 1;
    unsigned pref = 0;
#pragma unroll
    for (int u = 0; u < CAP / 64; ++u) {
        const unsigned long long b = __ballot(kk[u] <= T);
        const int slot = (int)pref + (int)__popcll(b & lml);
        if (kk[u] <= T && slot < 64) cbuf[slot] = kk[u];
        pref += (unsigned)__popcll(b);
    }
    __syncthreads();
    const unsigned c32 = cbuf[lane];
    const int col = (int)(c32 & 0xFFFFu);
    const bool valid = (col < NN);
    const int sc = valid ? col : 0;
    const float* xr = x + (size_t)i * DI;    // uniform
    const float* xc = x + (size_t)sc * DI;
    double a = 0.0;
#pragma unroll 4
    for (int d = 0; d < DI; ++d)
        a = fma((double)xr[d], (double)xc[d], a);
    const float dd = (float)(sq64[i] + sq64[sc] - 2.0 * a);
    unsigned long long key =
        valid ? (((unsigned long long)fkey(dd) << 32) | (unsigned)col) : ~0ull;
#pragma unroll 1
    for (int k = 0; k < KNB; ++k) {
        unsigned long long m = key;
#pragma unroll
        for (int off = 32; off >= 1; off >>= 1) {
            const unsigned long long o = __shfl_xor(m, off);
            m = o < m ? o : m;
        }
        if (key == m) { key = ~0ull; nbr[(size_t)i * KNB + k] = (int)(m & 0xffffffffu); }
    }
}

// h_l = x@W_l + b_l ; h_r = x@W_r + b_r  (f32 vector FMA)
__global__ __launch_bounds__(256) void hgemm_k(
    const float* __restrict__ x, const float* __restrict__ Wl,
    const float* __restrict__ bl, const float* __restrict__ Wr,
    const float* __restrict__ br, float* __restrict__ hl, float* __restrict__ hr)
{
    const int c = threadIdx.x;
    const int r0 = blockIdx.x * RB;
    float accl[RB], accr[RB];
    const float blv = bl[c], brv = br[c];
#pragma unroll
    for (int r = 0; r < RB; ++r) { accl[r] = blv; accr[r] = brv; }
    for (int d = 0; d < DI; ++d) {
        const float wl = Wl[d * DO + c];
        const float wr = Wr[d * DO + c];
#pragma unroll
        for (int r = 0; r < RB; ++r) {
            const float xv = x[(size_t)(r0 + r) * DI + d];  // wave-uniform
            accl[r] = fmaf(xv, wl, accl[r]);
            accr[r] = fmaf(xv, wr, accr[r]);
        }
    }
#pragma unroll
    for (int r = 0; r < RB; ++r) {
        hl[(size_t)(r0 + r) * DO + c] = accl[r];
        hr[(size_t)(r0 + r) * DO + c] = accr[r];
    }
}

// attention epilogue: block=row, thread=output dim
__global__ __launch_bounds__(256) void gat_k(
    const float* __restrict__ hl, const float* __restrict__ hr,
    const int* __restrict__ nbr, const float* __restrict__ att,
    const float* __restrict__ bias, float* __restrict__ out)
{
    __shared__ int src[NSRC];
    __shared__ float eP[NSRC][4];
    __shared__ float eS[NSRC];
    const int i = blockIdx.x, t = threadIdx.x;
    if (t < KNB) src[t] = nbr[(size_t)i * KNB + t];
    if (t == KNB) src[KNB] = i;   // self-loop appended last
    __syncthreads();
    const float at  = att[t];
    const float hrv = hr[(size_t)i * DO + t];
    float hlv[NSRC];
#pragma unroll
    for (int k = 0; k < NSRC; ++k) {
        const float v = hl[(size_t)src[k] * DO + t];
        hlv[k] = v;
        const float z = v + hrv;
        float p = (z > 0.f ? z : NEG * z) * at;
#pragma unroll
        for (int off = 32; off >= 1; off >>= 1) p += __shfl_xor(p, off);
        if ((t & 63) == 0) eP[k][t >> 6] = p;
    }
    __syncthreads();
    if (t < NSRC) eS[t] = eP[t][0] + eP[t][1] + eP[t][2] + eP[t][3];
    __syncthreads();
    float m = eS[0];
#pragma unroll
    for (int k = 1; k < NSRC; ++k) m = fmaxf(m, eS[k]);
    float w[NSRC];
    float ssum = 0.f;
#pragma unroll
    for (int k = 0; k < NSRC; ++k) { w[k] = expf(eS[k] - m); ssum += w[k]; }
    const float inv = 1.f / ssum;
    float o = bias[t];
#pragma unroll
    for (int k = 0; k < NSRC; ++k) o = fmaf(w[k] * inv, hlv[k], o);
    out[(size_t)i * DO + t] = o;
}

extern "C" void kernel_launch(void* const* d_in, const int* in_sizes, int n_in,
                              void* d_out, int out_size, void* d_ws, size_t ws_size,
                              hipStream_t stream) {
    const float* x    = (const float*)d_in[0];
    const float* Wl   = (const float*)d_in[1];
    const float* bl   = (const float*)d_in[2];
    const float* Wr   = (const float*)d_in[3];
    const float* br   = (const float*)d_in[4];
    const float* att  = (const float*)d_in[5];
    const float* bias = (const float*)d_in[6];
    float* out = (float*)d_out;

    char* ws = (char*)d_ws;
    // layout (bytes); hl/hr alias cand (cand fully consumed by rerank_select_k
    // before hgemm_k writes hl/hr — stream-ordered):
    unsigned short* aF  = (unsigned short*)(ws + 0);          //  5,128,192
    unsigned short* Bh  = (unsigned short*)(ws + 5128192);    //  2,621,440
    double* sq64 = (double*)(ws + 7749632);                   //     80,128
    float*  sq32 = (float*)(ws + 7829760);                    //     40,960
    unsigned* Trow = (unsigned*)(ws + 7870720);               //     40,064
    unsigned* cnt  = (unsigned*)(ws + 7910784);               //     40,064
    int*    nbr  = (int*)(ws + 7950848);                      //  1,280,000
    unsigned* cand = (unsigned*)(ws + 9230848);               // 40,960,000
    float*  hl   = (float*)(ws + 9230848);                    // 10,240,000 (alias)
    float*  hr   = (float*)(ws + 19470848);                   // 10,240,000 (alias)
    // total = 50,190,848 bytes

    hipMemsetAsync(cnt, 0, ATILE * 16 * sizeof(unsigned), stream);
    prep_k<<<dim3(NTILE), 256, 0, stream>>>(x, aF, Bh, sq64, sq32);
    thresh_k<<<dim3(ATILE), 256, 0, stream>>>(aF, Bh, sq32, Trow);
    knn_emit_k<<<dim3(ATILE / 2, NP2 / 512), 256, 0, stream>>>(aF, Bh, sq32, Trow, cnt, cand);
    rerank_select_k<<<dim3(NN), 64, 0, stream>>>(x, sq64, cand, cnt, nbr);
    hgemm_k<<<dim3(NN / RB), 256, 0, stream>>>(x, Wl, bl, Wr, br, hl, hr);
    gat_k<<<dim3(NN), 256, 0, stream>>>(hl, hr, nbr, att, bias, out);
}

// Round 9
// 458.789 us; speedup vs baseline: 1.3119x; 1.3119x over previous
//
#include <hip/hip_runtime.h>

#define NN     10000
#define DI     128
#define DO     256
#define KNB    32
#define NSRC   33      // 32 neighbors + self
#define RB     16
#define NP2    10240
#define NTILE  640     // NP2/16 col tiles
#define ATILE  626     // row tiles (covers 10016 rows, pad zeroed)
#define NCB    20      // col blocks of 512
#define SEG    64      // per-(row,colblock) candidate capacity
#define NEG    0.2f

typedef __attribute__((ext_vector_type(8))) short bf16x8;
typedef __attribute__((ext_vector_type(4))) float f32x4;

// monotone map f32 -> u32 preserving < order (handles negatives)
__device__ __forceinline__ unsigned fkey(float f) {
    unsigned u = __float_as_uint(f);
    return (u & 0x80000000u) ? ~u : (u | 0x80000000u);
}
__device__ __forceinline__ unsigned short bf16rne(float f) {
    unsigned u = __float_as_uint(f);
    unsigned r = u + 0x7FFFu + ((u >> 16) & 1u);
    return (unsigned short)(r >> 16);
}

// Fused prep: stage 16 rows of x, emit A-fragments (hi+lo planes), B-fragments
// (hi plane only; A-side split carries the precision), f64/f32 squared norms.
__global__ __launch_bounds__(256) void prep_k(const float* __restrict__ x,
    unsigned short* __restrict__ aF, unsigned short* __restrict__ Bh,
    double* __restrict__ sq64, float* __restrict__ sq32)
{
    __shared__ float xs[16][132];   // +4 pad: conflict-free strided reads
    const int t = threadIdx.x;
    const int tile = blockIdx.x;
    const int i0 = tile * 16;
#pragma unroll
    for (int q = 0; q < 2; ++q) {
        const int idx = t + 256 * q;
        const int r = idx >> 5, c4 = idx & 31;
        float4 v = make_float4(0.f, 0.f, 0.f, 0.f);
        if (i0 + r < NN) v = *(const float4*)(x + (size_t)(i0 + r) * DI + c4 * 4);
        *(float4*)&xs[r][c4 * 4] = v;
    }
    __syncthreads();
    const int ks = t >> 6, flane = t & 63;
    const int srow = flane & 15;
    const int kb = ks * 32 + ((flane >> 4) & 3) * 8;
    unsigned hi2[4], lo2[4];
#pragma unroll
    for (int j = 0; j < 4; ++j) {
        const float v0 = xs[srow][kb + 2 * j], v1 = xs[srow][kb + 2 * j + 1];
        const unsigned short h0 = bf16rne(v0), h1 = bf16rne(v1);
        const unsigned short l0 = bf16rne(v0 - __uint_as_float((unsigned)h0 << 16));
        const unsigned short l1 = bf16rne(v1 - __uint_as_float((unsigned)h1 << 16));
        hi2[j] = (unsigned)h0 | ((unsigned)h1 << 16);
        lo2[j] = (unsigned)l0 | ((unsigned)l1 << 16);
    }
    *(uint4*)(Bh + ((size_t)(tile * 4 + ks) * 64 + flane) * 8) =
        make_uint4(hi2[0], hi2[1], hi2[2], hi2[3]);
    if (tile < ATILE) {
        unsigned short* pa = aF + (((size_t)(tile * 4 + ks) * 2) * 64 + flane) * 8;
        *(uint4*)pa         = make_uint4(hi2[0], hi2[1], hi2[2], hi2[3]);
        *(uint4*)(pa + 512) = make_uint4(lo2[0], lo2[1], lo2[2], lo2[3]);
    }
    const int row = t >> 4, sub = t & 15;
    double s = 0.0;
#pragma unroll
    for (int q = 0; q < 8; ++q) {
        const float v = xs[row][sub * 8 + q];
        s = fma((double)v, (double)v, s);
    }
#pragma unroll
    for (int off = 8; off >= 1; off >>= 1) s += __shfl_xor(s, off);
    if (sub == 0) {
        const int gi = i0 + row;
        sq32[gi] = (gi < NN) ? (float)s : 0.f;
        if (gi < ATILE * 16) sq64[gi] = s;
    }
}

// Per-row threshold from the chunk-0 sample: 16th-smallest u16 key of the
// row's 512 distances -> Trow raw-u32 bound (bitwise-consistent with emit).
__global__ __launch_bounds__(256) void thresh_k(
    const unsigned short* __restrict__ aF, const unsigned short* __restrict__ Bh,
    const float* __restrict__ sq32, unsigned* __restrict__ Trow)
{
    __shared__ unsigned short dist16[RB][512];
    const int rt = blockIdx.x;
    const int r0 = rt * 16;
    const int t = threadIdx.x;
    const int wid = t >> 6, lane = t & 63;
    const int wbase = wid * 128, l15 = lane & 15, rgrp = (lane >> 4) * 4;

    bf16x8 ah[4], al[4];
#pragma unroll
    for (int ks = 0; ks < 4; ++ks) {
        const unsigned short* pa = aF + (((size_t)(rt * 4 + ks) * 2) * 64 + lane) * 8;
        ah[ks] = *(const bf16x8*)pa;
        al[ks] = *(const bf16x8*)(pa + 512);
    }
    float sqiv[4];
#pragma unroll
    for (int rg = 0; rg < 4; ++rg) sqiv[rg] = sq32[r0 + rgrp + rg];

#pragma unroll 1
    for (int ct = 0; ct < 8; ++ct) {
        const int ctg = wid * 8 + ct;
        bf16x8 bh[4];
#pragma unroll
        for (int ks = 0; ks < 4; ++ks)
            bh[ks] = *(const bf16x8*)(Bh + ((size_t)(ctg * 4 + ks) * 64 + lane) * 8);
        f32x4 acc = {0.f, 0.f, 0.f, 0.f};
#pragma unroll
        for (int ks = 0; ks < 4; ++ks) {
            acc = __builtin_amdgcn_mfma_f32_16x16x32_bf16(ah[ks], bh[ks], acc, 0, 0, 0);
            acc = __builtin_amdgcn_mfma_f32_16x16x32_bf16(al[ks], bh[ks], acc, 0, 0, 0);
        }
        const int col = wbase + ct * 16 + l15;
        const float sqj = sq32[col];
#pragma unroll
        for (int rg = 0; rg < 4; ++rg) {
            const int row = r0 + rgrp + rg;
            const float dd = __builtin_fmaf(-2.f, acc[rg], sqiv[rg] + sqj);
            unsigned k16 = (__float_as_uint(dd) >> 16) | 0x8000u;
            if (col >= NN || col == row) k16 = 0xFFFFu;
            dist16[rgrp + rg][col] = (unsigned short)k16;
        }
    }
    __syncthreads();

#pragma unroll 1
    for (int rr = 0; rr < 4; ++rr) {
        const int r = wid * 4 + rr;
        unsigned kk[8];
#pragma unroll
        for (int u = 0; u < 8; ++u) kk[u] = dist16[r][lane + 64 * u];
        unsigned lo = 0, hi = 0xFFFFu;
#pragma unroll 1
        for (int it = 0; it < 16; ++it) {
            const unsigned mid = (lo + hi) >> 1;
            int c2 = 0;
#pragma unroll
            for (int u = 0; u < 8; ++u)
                c2 += (int)__popcll(__ballot(kk[u] <= mid));
            if (c2 >= 16) hi = mid; else lo = mid;
        }
        if (lane == 0) Trow[r0 + r] = ((hi & 0x7FFFu) << 16) | 0xFFFFu;
    }
}

// Main pass: 32 rows x 512 cols per block, 2-MFMA A-split distances, B-fragment
// prefetch, threshold compare, LDS-atomic segmented append (no global atomics).
__global__ __launch_bounds__(256) void knn_emit_k(
    const unsigned short* __restrict__ aF, const unsigned short* __restrict__ Bh,
    const float* __restrict__ sq32, const unsigned* __restrict__ Trow,
    unsigned short* __restrict__ cnt2, unsigned* __restrict__ cand)
{
    __shared__ unsigned lcnt[32];
    const int r0 = blockIdx.x * 32;
    const int cbase = blockIdx.y * 512;
    const int t = threadIdx.x;
    const int wid = t >> 6, lane = t & 63;
    const int wbase = wid * 128, l15 = lane & 15, rgrp = (lane >> 4) * 4;
    if (t < 32) lcnt[t] = 0;

    bf16x8 ah[2][4], al[2][4];
#pragma unroll
    for (int rt2 = 0; rt2 < 2; ++rt2)
#pragma unroll
        for (int ks = 0; ks < 4; ++ks) {
            const int rt = (r0 >> 4) + rt2;
            const unsigned short* pa = aF + (((size_t)(rt * 4 + ks) * 2) * 64 + lane) * 8;
            ah[rt2][ks] = *(const bf16x8*)pa;
            al[rt2][ks] = *(const bf16x8*)(pa + 512);
        }
    float sqiv[2][4];
    unsigned TUv[2][4];
#pragma unroll
    for (int rt2 = 0; rt2 < 2; ++rt2)
#pragma unroll
        for (int rg = 0; rg < 4; ++rg) {
            const int row = r0 + rt2 * 16 + rgrp + rg;
            sqiv[rt2][rg] = sq32[row];
            TUv[rt2][rg] = Trow[row];
        }
    __syncthreads();

#define EMIT(ACC, RT2) { \
    _Pragma("unroll") \
    for (int rg = 0; rg < 4; ++rg) { \
        const int lrow = (RT2) * 16 + rgrp + rg; \
        const int row = r0 + lrow; \
        const float dd = __builtin_fmaf(-2.f, (ACC)[rg], sqiv[RT2][rg] + sqj); \
        const unsigned raw = __float_as_uint(dd); \
        const bool pass = (raw <= TUv[RT2][rg]) && (col < NN) && (col != row) && (row < NN); \
        const unsigned long long b = __ballot(pass); \
        const unsigned sub16 = (unsigned)((b >> (lane & 48)) & 0xFFFFull); \
        if (sub16) { \
            const int lead = (lane & 48) + (__ffs(sub16) - 1); \
            unsigned base = 0; \
            if (lane == lead) base = atomicAdd(&lcnt[lrow], (unsigned)__popc(sub16)); \
            base = __shfl(base, lead); \
            if (pass) { \
                const unsigned slot = base + (unsigned)__popc(sub16 & ((1u << l15) - 1)); \
                if (slot < SEG) \
                    cand[((size_t)row * NCB + blockIdx.y) * SEG + slot] = \
                        (((raw >> 16) | 0x8000u) << 16) | (unsigned)col; \
            } \
        } \
    } }

    const int ctg0 = (cbase >> 4) + wid * 8;
    bf16x8 bh[4];
#pragma unroll
    for (int ks = 0; ks < 4; ++ks)
        bh[ks] = *(const bf16x8*)(Bh + ((size_t)(ctg0 * 4 + ks) * 64 + lane) * 8);

#pragma unroll 1
    for (int ct = 0; ct < 8; ++ct) {
        bf16x8 bhn[4];
        if (ct < 7) {
#pragma unroll
            for (int ks = 0; ks < 4; ++ks)
                bhn[ks] = *(const bf16x8*)(Bh + ((size_t)((ctg0 + ct + 1) * 4 + ks) * 64 + lane) * 8);
        }
        f32x4 a0 = {0.f, 0.f, 0.f, 0.f}, a1 = {0.f, 0.f, 0.f, 0.f};
#pragma unroll
        for (int ks = 0; ks < 4; ++ks) {
            a0 = __builtin_amdgcn_mfma_f32_16x16x32_bf16(ah[0][ks], bh[ks], a0, 0, 0, 0);
            a0 = __builtin_amdgcn_mfma_f32_16x16x32_bf16(al[0][ks], bh[ks], a0, 0, 0, 0);
            a1 = __builtin_amdgcn_mfma_f32_16x16x32_bf16(ah[1][ks], bh[ks], a1, 0, 0, 0);
            a1 = __builtin_amdgcn_mfma_f32_16x16x32_bf16(al[1][ks], bh[ks], a1, 0, 0, 0);
        }
        const int col = cbase + wbase + ct * 16 + l15;
        const float sqj = sq32[col];
        EMIT(a0, 0)
        EMIT(a1, 1)
#pragma unroll
        for (int ks = 0; ks < 4; ++ks) bh[ks] = bhn[ks];
    }
#undef EMIT

    __syncthreads();
    if (t < 32) {
        const unsigned c = lcnt[t];
        cnt2[(size_t)(r0 + t) * NCB + blockIdx.y] =
            (unsigned short)(c < SEG ? c : SEG);
    }
}

// Per row: top-64 of the segmented candidates by packed (key16,col), exact f64
// rerank, emit final top-32 in (f32-dist, col) order. One wave per row.
__global__ void rerank_select_k(const float* __restrict__ x,
    const double* __restrict__ sq64, const unsigned* __restrict__ cand,
    const unsigned short* __restrict__ cnt2, int* __restrict__ nbr)
{
    __shared__ unsigned cbuf[64];
    const int i = blockIdx.x;
    const int lane = threadIdx.x;   // 64
    unsigned kk[NCB];
#pragma unroll
    for (int u = 0; u < NCB; ++u) {
        const int c = (int)cnt2[(size_t)i * NCB + u];
        kk[u] = (lane < c) ? cand[((size_t)i * NCB + u) * SEG + lane] : 0xFFFFFFFFu;
    }
    unsigned lo = 0, hi = 0xFFFFFFFFu;
#pragma unroll 1
    for (int it = 0; it < 32; ++it) {
        const unsigned mid = lo + ((hi - lo) >> 1);
        int c2 = 0;
#pragma unroll
        for (int u = 0; u < NCB; ++u)
            c2 += (int)__popcll(__ballot(kk[u] <= mid));
        if (c2 >= 64) hi = mid; else lo = mid;
    }
    const unsigned T = hi;
    const unsigned long long lml = (1ull << lane) - 1;
    unsigned pref = 0;
#pragma unroll
    for (int u = 0; u < NCB; ++u) {
        const unsigned long long b = __ballot(kk[u] <= T);
        const int slot = (int)pref + (int)__popcll(b & lml);
        if (kk[u] <= T && slot < 64) cbuf[slot] = kk[u];
        pref += (unsigned)__popcll(b);
    }
    __syncthreads();
    const unsigned c32 = cbuf[lane];
    const int col = (int)(c32 & 0xFFFFu);
    const bool valid = (col < NN);
    const int sc = valid ? col : 0;
    const float* xr = x + (size_t)i * DI;    // uniform
    const float* xc = x + (size_t)sc * DI;
    double a = 0.0;
#pragma unroll 4
    for (int d = 0; d < DI; ++d)
        a = fma((double)xr[d], (double)xc[d], a);
    const float dd = (float)(sq64[i] + sq64[sc] - 2.0 * a);
    unsigned long long key =
        valid ? (((unsigned long long)fkey(dd) << 32) | (unsigned)col) : ~0ull;
#pragma unroll 1
    for (int k = 0; k < KNB; ++k) {
        unsigned long long m = key;
#pragma unroll
        for (int off = 32; off >= 1; off >>= 1) {
            const unsigned long long o = __shfl_xor(m, off);
            m = o < m ? o : m;
        }
        if (key == m) { key = ~0ull; nbr[(size_t)i * KNB + k] = (int)(m & 0xffffffffu); }
    }
}

// h_l = x@W_l + b_l ; h_r = x@W_r + b_r  (f32 vector FMA)
__global__ __launch_bounds__(256) void hgemm_k(
    const float* __restrict__ x, const float* __restrict__ Wl,
    const float* __restrict__ bl, const float* __restrict__ Wr,
    const float* __restrict__ br, float* __restrict__ hl, float* __restrict__ hr)
{
    const int c = threadIdx.x;
    const int r0 = blockIdx.x * RB;
    float accl[RB], accr[RB];
    const float blv = bl[c], brv = br[c];
#pragma unroll
    for (int r = 0; r < RB; ++r) { accl[r] = blv; accr[r] = brv; }
    for (int d = 0; d < DI; ++d) {
        const float wl = Wl[d * DO + c];
        const float wr = Wr[d * DO + c];
#pragma unroll
        for (int r = 0; r < RB; ++r) {
            const float xv = x[(size_t)(r0 + r) * DI + d];  // wave-uniform
            accl[r] = fmaf(xv, wl, accl[r]);
            accr[r] = fmaf(xv, wr, accr[r]);
        }
    }
#pragma unroll
    for (int r = 0; r < RB; ++r) {
        hl[(size_t)(r0 + r) * DO + c] = accl[r];
        hr[(size_t)(r0 + r) * DO + c] = accr[r];
    }
}

// attention epilogue: block=row, thread=output dim
__global__ __launch_bounds__(256) void gat_k(
    const float* __restrict__ hl, const float* __restrict__ hr,
    const int* __restrict__ nbr, const float* __restrict__ att,
    const float* __restrict__ bias, float* __restrict__ out)
{
    __shared__ int src[NSRC];
    __shared__ float eP[NSRC][4];
    __shared__ float eS[NSRC];
    const int i = blockIdx.x, t = threadIdx.x;
    if (t < KNB) src[t] = nbr[(size_t)i * KNB + t];
    if (t == KNB) src[KNB] = i;   // self-loop appended last
    __syncthreads();
    const float at  = att[t];
    const float hrv = hr[(size_t)i * DO + t];
    float hlv[NSRC];
#pragma unroll
    for (int k = 0; k < NSRC; ++k) {
        const float v = hl[(size_t)src[k] * DO + t];
        hlv[k] = v;
        const float z = v + hrv;
        float p = (z > 0.f ? z : NEG * z) * at;
#pragma unroll
        for (int off = 32; off >= 1; off >>= 1) p += __shfl_xor(p, off);
        if ((t & 63) == 0) eP[k][t >> 6] = p;
    }
    __syncthreads();
    if (t < NSRC) eS[t] = eP[t][0] + eP[t][1] + eP[t][2] + eP[t][3];
    __syncthreads();
    float m = eS[0];
#pragma unroll
    for (int k = 1; k < NSRC; ++k) m = fmaxf(m, eS[k]);
    float w[NSRC];
    float ssum = 0.f;
#pragma unroll
    for (int k = 0; k < NSRC; ++k) { w[k] = expf(eS[k] - m); ssum += w[k]; }
    const float inv = 1.f / ssum;
    float o = bias[t];
#pragma unroll
    for (int k = 0; k < NSRC; ++k) o = fmaf(w[k] * inv, hlv[k], o);
    out[(size_t)i * DO + t] = o;
}

extern "C" void kernel_launch(void* const* d_in, const int* in_sizes, int n_in,
                              void* d_out, int out_size, void* d_ws, size_t ws_size,
                              hipStream_t stream) {
    const float* x    = (const float*)d_in[0];
    const float* Wl   = (const float*)d_in[1];
    const float* bl   = (const float*)d_in[2];
    const float* Wr   = (const float*)d_in[3];
    const float* br   = (const float*)d_in[4];
    const float* att  = (const float*)d_in[5];
    const float* bias = (const float*)d_in[6];
    float* out = (float*)d_out;

    char* ws = (char*)d_ws;
    // layout (bytes); hl/hr alias cand (cand fully consumed by rerank_select_k
    // before hgemm_k writes hl/hr — stream-ordered):
    unsigned short* aF  = (unsigned short*)(ws + 0);          //  5,128,192
    unsigned short* Bh  = (unsigned short*)(ws + 5128192);    //  2,621,440
    double* sq64 = (double*)(ws + 7749632);                   //     80,128
    float*  sq32 = (float*)(ws + 7829760);                    //     40,960
    unsigned* Trow = (unsigned*)(ws + 7870720);               //     40,064
    unsigned short* cnt2 = (unsigned short*)(ws + 7910784);   //    400,640
    int*    nbr  = (int*)(ws + 8311424);                      //  1,280,000
    unsigned* cand = (unsigned*)(ws + 9591424);               // 51,281,920
    float*  hl   = (float*)(ws + 9591424);                    // 10,240,000 (alias)
    float*  hr   = (float*)(ws + 19831424);                   // 10,240,000 (alias)
    // total = 60,873,344 bytes

    prep_k<<<dim3(NTILE), 256, 0, stream>>>(x, aF, Bh, sq64, sq32);
    thresh_k<<<dim3(ATILE), 256, 0, stream>>>(aF, Bh, sq32, Trow);
    knn_emit_k<<<dim3(ATILE / 2, NCB), 256, 0, stream>>>(aF, Bh, sq32, Trow, cnt2, cand);
    rerank_select_k<<<dim3(NN), 64, 0, stream>>>(x, sq64, cand, cnt2, nbr);
    hgemm_k<<<dim3(NN / RB), 256, 0, stream>>>(x, Wl, bl, Wr, br, hl, hr);
    gat_k<<<dim3(NN), 256, 0, stream>>>(hl, hr, nbr, att, bias, out);
}

// Round 10
// 353.569 us; speedup vs baseline: 1.7023x; 1.2976x over previous
//
#include <hip/hip_runtime.h>
#include <hip/hip_fp16.h>

#define NN     10000
#define DI     128
#define DO     256
#define KNB    32
#define NSRC   33      // 32 neighbors + self
#define RB     16
#define NP2    10240
#define NTILE  640     // NP2/16 col tiles
#define ATILE  626     // row tiles (covers 10016 rows, pad zeroed)
#define NCB    20      // col blocks of 512
#define SEG    64      // per-(row,colblock) candidate capacity
#define NEG    0.2f

typedef __attribute__((ext_vector_type(8))) short bf16x8;
typedef __attribute__((ext_vector_type(4))) float f32x4;

// monotone map f32 -> u32 preserving < order (handles negatives)
__device__ __forceinline__ unsigned fkey(float f) {
    unsigned u = __float_as_uint(f);
    return (u & 0x80000000u) ? ~u : (u | 0x80000000u);
}
__device__ __forceinline__ unsigned short bf16rne(float f) {
    unsigned u = __float_as_uint(f);
    unsigned r = u + 0x7FFFu + ((u >> 16) & 1u);
    return (unsigned short)(r >> 16);
}

// Fused prep: stage 16 rows of x, emit A-fragments (hi+lo planes), B-fragments
// (hi plane only; A-side split carries the precision), f64/f32 squared norms.
__global__ __launch_bounds__(256) void prep_k(const float* __restrict__ x,
    unsigned short* __restrict__ aF, unsigned short* __restrict__ Bh,
    double* __restrict__ sq64, float* __restrict__ sq32)
{
    __shared__ float xs[16][132];   // +4 pad: conflict-free strided reads
    const int t = threadIdx.x;
    const int tile = blockIdx.x;
    const int i0 = tile * 16;
#pragma unroll
    for (int q = 0; q < 2; ++q) {
        const int idx = t + 256 * q;
        const int r = idx >> 5, c4 = idx & 31;
        float4 v = make_float4(0.f, 0.f, 0.f, 0.f);
        if (i0 + r < NN) v = *(const float4*)(x + (size_t)(i0 + r) * DI + c4 * 4);
        *(float4*)&xs[r][c4 * 4] = v;
    }
    __syncthreads();
    const int ks = t >> 6, flane = t & 63;
    const int srow = flane & 15;
    const int kb = ks * 32 + ((flane >> 4) & 3) * 8;
    unsigned hi2[4], lo2[4];
#pragma unroll
    for (int j = 0; j < 4; ++j) {
        const float v0 = xs[srow][kb + 2 * j], v1 = xs[srow][kb + 2 * j + 1];
        const unsigned short h0 = bf16rne(v0), h1 = bf16rne(v1);
        const unsigned short l0 = bf16rne(v0 - __uint_as_float((unsigned)h0 << 16));
        const unsigned short l1 = bf16rne(v1 - __uint_as_float((unsigned)h1 << 16));
        hi2[j] = (unsigned)h0 | ((unsigned)h1 << 16);
        lo2[j] = (unsigned)l0 | ((unsigned)l1 << 16);
    }
    *(uint4*)(Bh + ((size_t)(tile * 4 + ks) * 64 + flane) * 8) =
        make_uint4(hi2[0], hi2[1], hi2[2], hi2[3]);
    if (tile < ATILE) {
        unsigned short* pa = aF + (((size_t)(tile * 4 + ks) * 2) * 64 + flane) * 8;
        *(uint4*)pa         = make_uint4(hi2[0], hi2[1], hi2[2], hi2[3]);
        *(uint4*)(pa + 512) = make_uint4(lo2[0], lo2[1], lo2[2], lo2[3]);
    }
    const int row = t >> 4, sub = t & 15;
    double s = 0.0;
#pragma unroll
    for (int q = 0; q < 8; ++q) {
        const float v = xs[row][sub * 8 + q];
        s = fma((double)v, (double)v, s);
    }
#pragma unroll
    for (int off = 8; off >= 1; off >>= 1) s += __shfl_xor(s, off);
    if (sub == 0) {
        const int gi = i0 + row;
        sq32[gi] = (gi < NN) ? (float)s : 0.f;
        if (gi < ATILE * 16) sq64[gi] = s;
    }
}

// Per-row threshold from the chunk-0 sample: 16th-smallest u16 key of the
// row's 512 distances -> Trow raw-u32 bound (bitwise-consistent with emit).
__global__ __launch_bounds__(256) void thresh_k(
    const unsigned short* __restrict__ aF, const unsigned short* __restrict__ Bh,
    const float* __restrict__ sq32, unsigned* __restrict__ Trow)
{
    __shared__ unsigned short dist16[RB][512];
    const int rt = blockIdx.x;
    const int r0 = rt * 16;
    const int t = threadIdx.x;
    const int wid = t >> 6, lane = t & 63;
    const int wbase = wid * 128, l15 = lane & 15, rgrp = (lane >> 4) * 4;

    bf16x8 ah[4], al[4];
#pragma unroll
    for (int ks = 0; ks < 4; ++ks) {
        const unsigned short* pa = aF + (((size_t)(rt * 4 + ks) * 2) * 64 + lane) * 8;
        ah[ks] = *(const bf16x8*)pa;
        al[ks] = *(const bf16x8*)(pa + 512);
    }
    float sqiv[4];
#pragma unroll
    for (int rg = 0; rg < 4; ++rg) sqiv[rg] = sq32[r0 + rgrp + rg];

#pragma unroll 1
    for (int ct = 0; ct < 8; ++ct) {
        const int ctg = wid * 8 + ct;
        bf16x8 bh[4];
#pragma unroll
        for (int ks = 0; ks < 4; ++ks)
            bh[ks] = *(const bf16x8*)(Bh + ((size_t)(ctg * 4 + ks) * 64 + lane) * 8);
        f32x4 acc = {0.f, 0.f, 0.f, 0.f};
#pragma unroll
        for (int ks = 0; ks < 4; ++ks) {
            acc = __builtin_amdgcn_mfma_f32_16x16x32_bf16(ah[ks], bh[ks], acc, 0, 0, 0);
            acc = __builtin_amdgcn_mfma_f32_16x16x32_bf16(al[ks], bh[ks], acc, 0, 0, 0);
        }
        const int col = wbase + ct * 16 + l15;
        const float sqj = sq32[col];
#pragma unroll
        for (int rg = 0; rg < 4; ++rg) {
            const int row = r0 + rgrp + rg;
            const float dd = __builtin_fmaf(-2.f, acc[rg], sqiv[rg] + sqj);
            unsigned k16 = (__float_as_uint(dd) >> 16) | 0x8000u;
            if (col >= NN || col == row) k16 = 0xFFFFu;
            dist16[rgrp + rg][col] = (unsigned short)k16;
        }
    }
    __syncthreads();

#pragma unroll 1
    for (int rr = 0; rr < 4; ++rr) {
        const int r = wid * 4 + rr;
        unsigned kk[8];
#pragma unroll
        for (int u = 0; u < 8; ++u) kk[u] = dist16[r][lane + 64 * u];
        unsigned lo = 0, hi = 0xFFFFu;
#pragma unroll 1
        for (int it = 0; it < 16; ++it) {
            const unsigned mid = (lo + hi) >> 1;
            int c2 = 0;
#pragma unroll
            for (int u = 0; u < 8; ++u)
                c2 += (int)__popcll(__ballot(kk[u] <= mid));
            if (c2 >= 16) hi = mid; else lo = mid;
        }
        if (lane == 0) Trow[r0 + r] = ((hi & 0x7FFFu) << 16) | 0xFFFFu;
    }
}

// Main pass: 32 rows x 512 cols per block, 2-MFMA A-split distances, B-fragment
// prefetch, threshold compare, LDS-atomic segmented append (no global atomics).
__global__ __launch_bounds__(256) void knn_emit_k(
    const unsigned short* __restrict__ aF, const unsigned short* __restrict__ Bh,
    const float* __restrict__ sq32, const unsigned* __restrict__ Trow,
    unsigned short* __restrict__ cnt2, unsigned* __restrict__ cand)
{
    __shared__ unsigned lcnt[32];
    const int r0 = blockIdx.x * 32;
    const int cbase = blockIdx.y * 512;
    const int t = threadIdx.x;
    const int wid = t >> 6, lane = t & 63;
    const int wbase = wid * 128, l15 = lane & 15, rgrp = (lane >> 4) * 4;
    if (t < 32) lcnt[t] = 0;

    bf16x8 ah[2][4], al[2][4];
#pragma unroll
    for (int rt2 = 0; rt2 < 2; ++rt2)
#pragma unroll
        for (int ks = 0; ks < 4; ++ks) {
            const int rt = (r0 >> 4) + rt2;
            const unsigned short* pa = aF + (((size_t)(rt * 4 + ks) * 2) * 64 + lane) * 8;
            ah[rt2][ks] = *(const bf16x8*)pa;
            al[rt2][ks] = *(const bf16x8*)(pa + 512);
        }
    float sqiv[2][4];
    unsigned TUv[2][4];
#pragma unroll
    for (int rt2 = 0; rt2 < 2; ++rt2)
#pragma unroll
        for (int rg = 0; rg < 4; ++rg) {
            const int row = r0 + rt2 * 16 + rgrp + rg;
            sqiv[rt2][rg] = sq32[row];
            TUv[rt2][rg] = Trow[row];
        }
    __syncthreads();

#define EMIT(ACC, RT2) { \
    _Pragma("unroll") \
    for (int rg = 0; rg < 4; ++rg) { \
        const int lrow = (RT2) * 16 + rgrp + rg; \
        const int row = r0 + lrow; \
        const float dd = __builtin_fmaf(-2.f, (ACC)[rg], sqiv[RT2][rg] + sqj); \
        const unsigned raw = __float_as_uint(dd); \
        const bool pass = (raw <= TUv[RT2][rg]) && (col < NN) && (col != row) && (row < NN); \
        const unsigned long long b = __ballot(pass); \
        const unsigned sub16 = (unsigned)((b >> (lane & 48)) & 0xFFFFull); \
        if (sub16) { \
            const int lead = (lane & 48) + (__ffs(sub16) - 1); \
            unsigned base = 0; \
            if (lane == lead) base = atomicAdd(&lcnt[lrow], (unsigned)__popc(sub16)); \
            base = __shfl(base, lead); \
            if (pass) { \
                const unsigned slot = base + (unsigned)__popc(sub16 & ((1u << l15) - 1)); \
                if (slot < SEG) \
                    cand[((size_t)row * NCB + blockIdx.y) * SEG + slot] = \
                        (((raw >> 16) | 0x8000u) << 16) | (unsigned)col; \
            } \
        } \
    } }

    const int ctg0 = (cbase >> 4) + wid * 8;
    bf16x8 bh[4];
#pragma unroll
    for (int ks = 0; ks < 4; ++ks)
        bh[ks] = *(const bf16x8*)(Bh + ((size_t)(ctg0 * 4 + ks) * 64 + lane) * 8);

#pragma unroll 1
    for (int ct = 0; ct < 8; ++ct) {
        bf16x8 bhn[4];
        if (ct < 7) {
#pragma unroll
            for (int ks = 0; ks < 4; ++ks)
                bhn[ks] = *(const bf16x8*)(Bh + ((size_t)((ctg0 + ct + 1) * 4 + ks) * 64 + lane) * 8);
        }
        f32x4 a0 = {0.f, 0.f, 0.f, 0.f}, a1 = {0.f, 0.f, 0.f, 0.f};
#pragma unroll
        for (int ks = 0; ks < 4; ++ks) {
            a0 = __builtin_amdgcn_mfma_f32_16x16x32_bf16(ah[0][ks], bh[ks], a0, 0, 0, 0);
            a0 = __builtin_amdgcn_mfma_f32_16x16x32_bf16(al[0][ks], bh[ks], a0, 0, 0, 0);
            a1 = __builtin_amdgcn_mfma_f32_16x16x32_bf16(ah[1][ks], bh[ks], a1, 0, 0, 0);
            a1 = __builtin_amdgcn_mfma_f32_16x16x32_bf16(al[1][ks], bh[ks], a1, 0, 0, 0);
        }
        const int col = cbase + wbase + ct * 16 + l15;
        const float sqj = sq32[col];
        EMIT(a0, 0)
        EMIT(a1, 1)
#pragma unroll
        for (int ks = 0; ks < 4; ++ks) bh[ks] = bhn[ks];
    }
#undef EMIT

    __syncthreads();
    if (t < 32) {
        const unsigned c = lcnt[t];
        cnt2[(size_t)(r0 + t) * NCB + blockIdx.y] =
            (unsigned short)(c < SEG ? c : SEG);
    }
}

// Per row: top-64 of the segmented candidates by packed (key16,col), exact f64
// rerank, emit final top-32 in (f32-dist, col) order. One wave per row.
__global__ void rerank_select_k(const float* __restrict__ x,
    const double* __restrict__ sq64, const unsigned* __restrict__ cand,
    const unsigned short* __restrict__ cnt2, int* __restrict__ nbr)
{
    __shared__ unsigned cbuf[64];
    const int i = blockIdx.x;
    const int lane = threadIdx.x;   // 64
    unsigned kk[NCB];
#pragma unroll
    for (int u = 0; u < NCB; ++u) {
        const int c = (int)cnt2[(size_t)i * NCB + u];
        kk[u] = (lane < c) ? cand[((size_t)i * NCB + u) * SEG + lane] : 0xFFFFFFFFu;
    }
    unsigned lo = 0, hi = 0xFFFFFFFFu;
#pragma unroll 1
    for (int it = 0; it < 32; ++it) {
        const unsigned mid = lo + ((hi - lo) >> 1);
        int c2 = 0;
#pragma unroll
        for (int u = 0; u < NCB; ++u)
            c2 += (int)__popcll(__ballot(kk[u] <= mid));
        if (c2 >= 64) hi = mid; else lo = mid;
    }
    const unsigned T = hi;
    const unsigned long long lml = (1ull << lane) - 1;
    unsigned pref = 0;
#pragma unroll
    for (int u = 0; u < NCB; ++u) {
        const unsigned long long b = __ballot(kk[u] <= T);
        const int slot = (int)pref + (int)__popcll(b & lml);
        if (kk[u] <= T && slot < 64) cbuf[slot] = kk[u];
        pref += (unsigned)__popcll(b);
    }
    __syncthreads();
    const unsigned c32 = cbuf[lane];
    const int col = (int)(c32 & 0xFFFFu);
    const bool valid = (col < NN);
    const int sc = valid ? col : 0;
    const float* xr = x + (size_t)i * DI;    // uniform
    const float* xc = x + (size_t)sc * DI;
    double a = 0.0;
#pragma unroll 4
    for (int d = 0; d < DI; ++d)
        a = fma((double)xr[d], (double)xc[d], a);
    const float dd = (float)(sq64[i] + sq64[sc] - 2.0 * a);
    unsigned long long key =
        valid ? (((unsigned long long)fkey(dd) << 32) | (unsigned)col) : ~0ull;
#pragma unroll 1
    for (int k = 0; k < KNB; ++k) {
        unsigned long long m = key;
#pragma unroll
        for (int off = 32; off >= 1; off >>= 1) {
            const unsigned long long o = __shfl_xor(m, off);
            m = o < m ? o : m;
        }
        if (key == m) { key = ~0ull; nbr[(size_t)i * KNB + k] = (int)(m & 0xffffffffu); }
    }
}

// h_l = x@W_l + b_l (fp16 out, for gat gather); h_r = x@W_r + b_r (f32)
__global__ __launch_bounds__(256) void hgemm_k(
    const float* __restrict__ x, const float* __restrict__ Wl,
    const float* __restrict__ bl, const float* __restrict__ Wr,
    const float* __restrict__ br, __half* __restrict__ hl16, float* __restrict__ hr)
{
    const int c = threadIdx.x;
    const int r0 = blockIdx.x * RB;
    float accl[RB], accr[RB];
    const float blv = bl[c], brv = br[c];
#pragma unroll
    for (int r = 0; r < RB; ++r) { accl[r] = blv; accr[r] = brv; }
    for (int d = 0; d < DI; ++d) {
        const float wl = Wl[d * DO + c];
        const float wr = Wr[d * DO + c];
#pragma unroll
        for (int r = 0; r < RB; ++r) {
            const float xv = x[(size_t)(r0 + r) * DI + d];  // wave-uniform
            accl[r] = fmaf(xv, wl, accl[r]);
            accr[r] = fmaf(xv, wr, accr[r]);
        }
    }
#pragma unroll
    for (int r = 0; r < RB; ++r) {
        hl16[(size_t)(r0 + r) * DO + c] = __float2half(accl[r]);
        hr[(size_t)(r0 + r) * DO + c] = accr[r];
    }
}

// attention epilogue: block=row. Stage all 33 hl16 rows in LDS once;
// e-phase: wave w owns k in {w, w+4, ...} (4 dims/lane, intra-wave reduce);
// softmax on wave 0; output phase reads LDS (2-way bank alias = free).
__global__ __launch_bounds__(256) void gat_k(
    const __half* __restrict__ hl16, const float* __restrict__ hr,
    const int* __restrict__ nbr, const float* __restrict__ att,
    const float* __restrict__ bias, float* __restrict__ out)
{
    __shared__ int src[NSRC];
    __shared__ __align__(16) __half hbuf[NSRC][DO];   // 16,896 B
    __shared__ float eS[NSRC];
    __shared__ float alphaS[NSRC];
    const int i = blockIdx.x, t = threadIdx.x;
    if (t < KNB) src[t] = nbr[(size_t)i * KNB + t];
    if (t == KNB) src[KNB] = i;   // self-loop appended last
    __syncthreads();

    {   // stage 33 rows: 32 threads x 16B per row
        const int sub = t & 31, rb = t >> 5;
#pragma unroll
        for (int s = 0; s < 5; ++s) {
            const int rk = s * 8 + rb;
            if (rk < NSRC)
                *(uint4*)&hbuf[rk][sub * 8] =
                    *(const uint4*)(hl16 + (size_t)src[rk] * DO + sub * 8);
        }
    }
    __syncthreads();

    const int wid = t >> 6, lane = t & 63;
    {
        const float4 hr4 = *(const float4*)(hr + (size_t)i * DO + lane * 4);
        const float4 at4 = *(const float4*)(att + lane * 4);
#pragma unroll 1
        for (int k = wid; k < NSRC; k += 4) {
            const __half2 h01 = *(const __half2*)&hbuf[k][lane * 4];
            const __half2 h23 = *(const __half2*)&hbuf[k][lane * 4 + 2];
            const float2 f01 = __half22float2(h01);
            const float2 f23 = __half22float2(h23);
            float z, p = 0.f;
            z = f01.x + hr4.x; p = fmaf(z > 0.f ? z : NEG * z, at4.x, p);
            z = f01.y + hr4.y; p = fmaf(z > 0.f ? z : NEG * z, at4.y, p);
            z = f23.x + hr4.z; p = fmaf(z > 0.f ? z : NEG * z, at4.z, p);
            z = f23.y + hr4.w; p = fmaf(z > 0.f ? z : NEG * z, at4.w, p);
#pragma unroll
            for (int off = 32; off >= 1; off >>= 1) p += __shfl_xor(p, off);
            if (lane == 0) eS[k] = p;
        }
    }
    __syncthreads();
    if (wid == 0) {
        const float v = (lane < NSRC) ? eS[lane] : -3.4e38f;
        float m = v;
#pragma unroll
        for (int off = 32; off >= 1; off >>= 1) m = fmaxf(m, __shfl_xor(m, off));
        float w = (lane < NSRC) ? __expf(v - m) : 0.f;
        float s = w;
#pragma unroll
        for (int off = 32; off >= 1; off >>= 1) s += __shfl_xor(s, off);
        if (lane < NSRC) alphaS[lane] = w / s;
    }
    __syncthreads();
    float o = bias[t];
#pragma unroll
    for (int k = 0; k < NSRC; ++k)
        o = fmaf(alphaS[k], __half2float(hbuf[k][t]), o);
    out[(size_t)i * DO + t] = o;
}

extern "C" void kernel_launch(void* const* d_in, const int* in_sizes, int n_in,
                              void* d_out, int out_size, void* d_ws, size_t ws_size,
                              hipStream_t stream) {
    const float* x    = (const float*)d_in[0];
    const float* Wl   = (const float*)d_in[1];
    const float* bl   = (const float*)d_in[2];
    const float* Wr   = (const float*)d_in[3];
    const float* br   = (const float*)d_in[4];
    const float* att  = (const float*)d_in[5];
    const float* bias = (const float*)d_in[6];
    float* out = (float*)d_out;

    char* ws = (char*)d_ws;
    // layout (bytes); hl16/hr alias cand (cand fully consumed by
    // rerank_select_k before hgemm_k writes them — stream-ordered):
    unsigned short* aF  = (unsigned short*)(ws + 0);          //  5,128,192
    unsigned short* Bh  = (unsigned short*)(ws + 5128192);    //  2,621,440
    double* sq64 = (double*)(ws + 7749632);                   //     80,128
    float*  sq32 = (float*)(ws + 7829760);                    //     40,960
    unsigned* Trow = (unsigned*)(ws + 7870720);               //     40,064
    unsigned short* cnt2 = (unsigned short*)(ws + 7910784);   //    400,640
    int*    nbr  = (int*)(ws + 8311424);                      //  1,280,000
    unsigned* cand = (unsigned*)(ws + 9591424);               // 51,281,920
    __half* hl16 = (__half*)(ws + 9591424);                   //  5,120,000 (alias)
    float*  hr   = (float*)(ws + 14711424);                   // 10,240,000 (alias)
    // total = 60,873,344 bytes

    prep_k<<<dim3(NTILE), 256, 0, stream>>>(x, aF, Bh, sq64, sq32);
    thresh_k<<<dim3(ATILE), 256, 0, stream>>>(aF, Bh, sq32, Trow);
    knn_emit_k<<<dim3(ATILE / 2, NCB), 256, 0, stream>>>(aF, Bh, sq32, Trow, cnt2, cand);
    rerank_select_k<<<dim3(NN), 64, 0, stream>>>(x, sq64, cand, cnt2, nbr);
    hgemm_k<<<dim3(NN / RB), 256, 0, stream>>>(x, Wl, bl, Wr, br, hl16, hr);
    gat_k<<<dim3(NN), 256, 0, stream>>>(hl16, hr, nbr, att, bias, out);
}

// Round 11
// 266.531 us; speedup vs baseline: 2.2582x; 1.3266x over previous
//
#include <hip/hip_runtime.h>
#include <hip/hip_fp16.h>

#define NN     10000
#define DI     128
#define DO     256
#define KNB    32
#define NSRC   33      // 32 neighbors + self
#define RB     16
#define NP2    10240
#define NTILE  640     // NP2/16 tiles (B side; A reuses these fragments)
#define ATILE  626     // row tiles (covers 10016 rows, pad zeroed)
#define NCB    20      // col blocks of 512
#define SEG    64      // per-(row,colblock) candidate capacity
#define NEG    0.2f

typedef __attribute__((ext_vector_type(8))) short bf16x8;
typedef __attribute__((ext_vector_type(4))) float f32x4;

// monotone map f32 -> u32 preserving < order (handles negatives)
__device__ __forceinline__ unsigned fkey(float f) {
    unsigned u = __float_as_uint(f);
    return (u & 0x80000000u) ? ~u : (u | 0x80000000u);
}
__device__ __forceinline__ unsigned short bf16rne(float f) {
    unsigned u = __float_as_uint(f);
    unsigned r = u + 0x7FFFu + ((u >> 16) & 1u);
    return (unsigned short)(r >> 16);
}

// Fused prep: stage 16 rows of x, emit bf16(hi) MFMA fragments (shared by the
// A and B operands — identical lane layout), f64/f32 squared norms.
__global__ __launch_bounds__(256) void prep_k(const float* __restrict__ x,
    unsigned short* __restrict__ Bh, double* __restrict__ sq64,
    float* __restrict__ sq32)
{
    __shared__ float xs[16][132];   // +4 pad: conflict-free strided reads
    const int t = threadIdx.x;
    const int tile = blockIdx.x;
    const int i0 = tile * 16;
#pragma unroll
    for (int q = 0; q < 2; ++q) {
        const int idx = t + 256 * q;
        const int r = idx >> 5, c4 = idx & 31;
        float4 v = make_float4(0.f, 0.f, 0.f, 0.f);
        if (i0 + r < NN) v = *(const float4*)(x + (size_t)(i0 + r) * DI + c4 * 4);
        *(float4*)&xs[r][c4 * 4] = v;
    }
    __syncthreads();
    const int ks = t >> 6, flane = t & 63;
    const int srow = flane & 15;
    const int kb = ks * 32 + ((flane >> 4) & 3) * 8;
    unsigned hi2[4];
#pragma unroll
    for (int j = 0; j < 4; ++j) {
        const float v0 = xs[srow][kb + 2 * j], v1 = xs[srow][kb + 2 * j + 1];
        hi2[j] = (unsigned)bf16rne(v0) | ((unsigned)bf16rne(v1) << 16);
    }
    *(uint4*)(Bh + ((size_t)(tile * 4 + ks) * 64 + flane) * 8) =
        make_uint4(hi2[0], hi2[1], hi2[2], hi2[3]);
    const int row = t >> 4, sub = t & 15;
    double s = 0.0;
#pragma unroll
    for (int q = 0; q < 8; ++q) {
        const float v = xs[row][sub * 8 + q];
        s = fma((double)v, (double)v, s);
    }
#pragma unroll
    for (int off = 8; off >= 1; off >>= 1) s += __shfl_xor(s, off);
    if (sub == 0) {
        const int gi = i0 + row;
        sq32[gi] = (gi < NN) ? (float)s : 0.f;
        if (gi < ATILE * 16) sq64[gi] = s;
    }
}

// Per-row threshold from the chunk-0 sample: 16th-smallest u16 key of the
// row's 512 distances -> Trow raw-u32 bound (bitwise-consistent with emit).
__global__ __launch_bounds__(256) void thresh_k(
    const unsigned short* __restrict__ Bh, const float* __restrict__ sq32,
    unsigned* __restrict__ Trow)
{
    __shared__ unsigned short dist16[RB][512];
    const int rt = blockIdx.x;
    const int r0 = rt * 16;
    const int t = threadIdx.x;
    const int wid = t >> 6, lane = t & 63;
    const int wbase = wid * 128, l15 = lane & 15, rgrp = (lane >> 4) * 4;

    bf16x8 ah[4];
#pragma unroll
    for (int ks = 0; ks < 4; ++ks)
        ah[ks] = *(const bf16x8*)(Bh + ((size_t)(rt * 4 + ks) * 64 + lane) * 8);
    float sqiv[4];
#pragma unroll
    for (int rg = 0; rg < 4; ++rg) sqiv[rg] = sq32[r0 + rgrp + rg];

#pragma unroll 1
    for (int ct = 0; ct < 8; ++ct) {
        const int ctg = wid * 8 + ct;
        bf16x8 bh[4];
#pragma unroll
        for (int ks = 0; ks < 4; ++ks)
            bh[ks] = *(const bf16x8*)(Bh + ((size_t)(ctg * 4 + ks) * 64 + lane) * 8);
        f32x4 acc = {0.f, 0.f, 0.f, 0.f};
#pragma unroll
        for (int ks = 0; ks < 4; ++ks)
            acc = __builtin_amdgcn_mfma_f32_16x16x32_bf16(ah[ks], bh[ks], acc, 0, 0, 0);
        const int col = wbase + ct * 16 + l15;
        const float sqj = sq32[col];
#pragma unroll
        for (int rg = 0; rg < 4; ++rg) {
            const int row = r0 + rgrp + rg;
            const float dd = __builtin_fmaf(-2.f, acc[rg], sqiv[rg] + sqj);
            unsigned k16 = (__float_as_uint(dd) >> 16) | 0x8000u;
            if (col >= NN || col == row) k16 = 0xFFFFu;
            dist16[rgrp + rg][col] = (unsigned short)k16;
        }
    }
    __syncthreads();

#pragma unroll 1
    for (int rr = 0; rr < 4; ++rr) {
        const int r = wid * 4 + rr;
        unsigned kk[8];
#pragma unroll
        for (int u = 0; u < 8; ++u) kk[u] = dist16[r][lane + 64 * u];
        unsigned lo = 0, hi = 0xFFFFu;
#pragma unroll 1
        for (int it = 0; it < 16; ++it) {
            const unsigned mid = (lo + hi) >> 1;
            int c2 = 0;
#pragma unroll
            for (int u = 0; u < 8; ++u)
                c2 += (int)__popcll(__ballot(kk[u] <= mid));
            if (c2 >= 16) hi = mid; else lo = mid;
        }
        if (lane == 0) Trow[r0 + r] = ((hi & 0x7FFFu) << 16) | 0xFFFFu;
    }
}

// Main pass: 32 rows x 512 cols per block, hi-only MFMA distances, threshold
// compare, per-lane LDS-atomic append into an LDS staging buffer, bulk copy
// to global (pads are 0xFFFFFFFF by construction; no cnt array needed).
__global__ __launch_bounds__(256) void knn_emit_k(
    const unsigned short* __restrict__ Bh, const float* __restrict__ sq32,
    const unsigned* __restrict__ Trow, unsigned* __restrict__ cand)
{
    __shared__ unsigned lcnt[32];
    __shared__ unsigned cbuf[32][SEG];   // 8 KB
    const int r0 = blockIdx.x * 32;
    const int cbase = blockIdx.y * 512;
    const int t = threadIdx.x;
    const int wid = t >> 6, lane = t & 63;
    const int wbase = wid * 128, l15 = lane & 15, rgrp = (lane >> 4) * 4;
    if (t < 32) lcnt[t] = 0;
    {
        unsigned* cb = &cbuf[0][0];
#pragma unroll
        for (int q = 0; q < (32 * SEG) / 256; ++q) cb[t + 256 * q] = 0xFFFFFFFFu;
    }

    bf16x8 ah[2][4];
#pragma unroll
    for (int rt2 = 0; rt2 < 2; ++rt2)
#pragma unroll
        for (int ks = 0; ks < 4; ++ks) {
            const int rt = (r0 >> 4) + rt2;
            ah[rt2][ks] = *(const bf16x8*)(Bh + ((size_t)(rt * 4 + ks) * 64 + lane) * 8);
        }
    float sqiv[2][4];
    unsigned TUv[2][4];
#pragma unroll
    for (int rt2 = 0; rt2 < 2; ++rt2)
#pragma unroll
        for (int rg = 0; rg < 4; ++rg) {
            const int row = r0 + rt2 * 16 + rgrp + rg;
            sqiv[rt2][rg] = sq32[row];
            TUv[rt2][rg] = Trow[row];
        }
    float sqjv[8];
#pragma unroll
    for (int ct = 0; ct < 8; ++ct)
        sqjv[ct] = sq32[cbase + wbase + ct * 16 + l15];
    __syncthreads();

    const int ctg0 = (cbase >> 4) + wid * 8;
    bf16x8 bh[4];
#pragma unroll
    for (int ks = 0; ks < 4; ++ks)
        bh[ks] = *(const bf16x8*)(Bh + ((size_t)(ctg0 * 4 + ks) * 64 + lane) * 8);

#pragma unroll 1
    for (int ct = 0; ct < 8; ++ct) {
        bf16x8 bhn[4];
        if (ct < 7) {
#pragma unroll
            for (int ks = 0; ks < 4; ++ks)
                bhn[ks] = *(const bf16x8*)(Bh + ((size_t)((ctg0 + ct + 1) * 4 + ks) * 64 + lane) * 8);
        }
        f32x4 a0 = {0.f, 0.f, 0.f, 0.f}, a1 = {0.f, 0.f, 0.f, 0.f};
#pragma unroll
        for (int ks = 0; ks < 4; ++ks) {
            a0 = __builtin_amdgcn_mfma_f32_16x16x32_bf16(ah[0][ks], bh[ks], a0, 0, 0, 0);
            a1 = __builtin_amdgcn_mfma_f32_16x16x32_bf16(ah[1][ks], bh[ks], a1, 0, 0, 0);
        }
        const int col = cbase + wbase + ct * 16 + l15;
        const float sqj = sqjv[ct];
#pragma unroll
        for (int rt2 = 0; rt2 < 2; ++rt2)
#pragma unroll
            for (int rg = 0; rg < 4; ++rg) {
                const int lrow = rt2 * 16 + rgrp + rg;
                const float dd = __builtin_fmaf(-2.f, (rt2 ? a1 : a0)[rg],
                                                sqiv[rt2][rg] + sqj);
                const unsigned raw = __float_as_uint(dd);
                if ((raw <= TUv[rt2][rg]) && (col < NN) && (col != r0 + lrow)) {
                    const unsigned slot = atomicAdd(&lcnt[lrow], 1u);
                    if (slot < SEG)
                        cbuf[lrow][slot] =
                            (((raw >> 16) | 0x8000u) << 16) | (unsigned)col;
                }
            }
#pragma unroll
        for (int ks = 0; ks < 4; ++ks) bh[ks] = bhn[ks];
    }

    __syncthreads();
#pragma unroll
    for (int q = 0; q < (32 * SEG) / 256; ++q) {
        const int idx = t + 256 * q;
        const int lr = idx >> 6, sl = idx & 63;
        cand[((size_t)(r0 + lr) * NCB + blockIdx.y) * SEG + sl] = cbuf[lr][sl];
    }
}

// Per row: top-64 of the segmented candidates by packed (key16,col), exact f64
// rerank, rank-scatter the final top-32 in (f32-dist, col) order. 1 wave/row.
__global__ void rerank_select_k(const float* __restrict__ x,
    const double* __restrict__ sq64, const unsigned* __restrict__ cand,
    int* __restrict__ nbr)
{
    __shared__ unsigned cbuf[64];
    const int i = blockIdx.x;
    const int lane = threadIdx.x;   // 64
    unsigned kk[NCB];
#pragma unroll
    for (int u = 0; u < NCB; ++u)
        kk[u] = cand[((size_t)i * NCB + u) * SEG + lane];   // pads = 0xFFFFFFFF
    unsigned lo = 0, hi = 0xFFFFFFFFu;
#pragma unroll 1
    for (int it = 0; it < 32; ++it) {
        const unsigned mid = lo + ((hi - lo) >> 1);
        int c2 = 0;
#pragma unroll
        for (int u = 0; u < NCB; ++u)
            c2 += (int)__popcll(__ballot(kk[u] <= mid));
        if (c2 >= 64) hi = mid; else lo = mid;
    }
    const unsigned T = hi;
    const unsigned long long lml = (1ull << lane) - 1;
    unsigned pref = 0;
#pragma unroll
    for (int u = 0; u < NCB; ++u) {
        const unsigned long long b = __ballot(kk[u] <= T);
        const int slot = (int)pref + (int)__popcll(b & lml);
        if (kk[u] <= T && slot < 64) cbuf[slot] = kk[u];
        pref += (unsigned)__popcll(b);
    }
    __syncthreads();
    const unsigned c32 = cbuf[lane];
    const int col = (int)(c32 & 0xFFFFu);
    const bool valid = (col < NN);
    const int sc = valid ? col : 0;
    const float* xr = x + (size_t)i * DI;    // uniform
    const float* xc = x + (size_t)sc * DI;
    double a = 0.0;
#pragma unroll 4
    for (int d = 0; d < DI; ++d)
        a = fma((double)xr[d], (double)xc[d], a);
    const float dd = (float)(sq64[i] + sq64[sc] - 2.0 * a);
    const unsigned long long key =
        valid ? (((unsigned long long)fkey(dd) << 32) | (unsigned)col) : ~0ull;
    int rank = 0;
#pragma unroll 1
    for (int l = 0; l < 64; ++l) {
        const unsigned long long kl = __shfl(key, l);
        rank += (kl < key) ? 1 : 0;
    }
    if (valid && rank < KNB) nbr[(size_t)i * KNB + rank] = col;
}

// h_l = x@W_l + b_l (fp16 out, for gat gather); h_r = x@W_r + b_r (f32)
__global__ __launch_bounds__(256) void hgemm_k(
    const float* __restrict__ x, const float* __restrict__ Wl,
    const float* __restrict__ bl, const float* __restrict__ Wr,
    const float* __restrict__ br, __half* __restrict__ hl16, float* __restrict__ hr)
{
    const int c = threadIdx.x;
    const int r0 = blockIdx.x * RB;
    float accl[RB], accr[RB];
    const float blv = bl[c], brv = br[c];
#pragma unroll
    for (int r = 0; r < RB; ++r) { accl[r] = blv; accr[r] = brv; }
    for (int d = 0; d < DI; ++d) {
        const float wl = Wl[d * DO + c];
        const float wr = Wr[d * DO + c];
#pragma unroll
        for (int r = 0; r < RB; ++r) {
            const float xv = x[(size_t)(r0 + r) * DI + d];  // wave-uniform
            accl[r] = fmaf(xv, wl, accl[r]);
            accr[r] = fmaf(xv, wr, accr[r]);
        }
    }
#pragma unroll
    for (int r = 0; r < RB; ++r) {
        hl16[(size_t)(r0 + r) * DO + c] = __float2half(accl[r]);
        hr[(size_t)(r0 + r) * DO + c] = accr[r];
    }
}

// attention epilogue: block=row. Stage all 33 hl16 rows in LDS once;
// e-phase: wave w owns k in {w, w+4, ...} (4 dims/lane, intra-wave reduce);
// softmax on wave 0; output phase reads LDS (2-way bank alias = free).
__global__ __launch_bounds__(256) void gat_k(
    const __half* __restrict__ hl16, const float* __restrict__ hr,
    const int* __restrict__ nbr, const float* __restrict__ att,
    const float* __restrict__ bias, float* __restrict__ out)
{
    __shared__ int src[NSRC];
    __shared__ __align__(16) __half hbuf[NSRC][DO];   // 16,896 B
    __shared__ float eS[NSRC];
    __shared__ float alphaS[NSRC];
    const int i = blockIdx.x, t = threadIdx.x;
    if (t < KNB) src[t] = nbr[(size_t)i * KNB + t];
    if (t == KNB) src[KNB] = i;   // self-loop appended last
    __syncthreads();

    {   // stage 33 rows: 32 threads x 16B per row
        const int sub = t & 31, rb = t >> 5;
#pragma unroll
        for (int s = 0; s < 5; ++s) {
            const int rk = s * 8 + rb;
            if (rk < NSRC)
                *(uint4*)&hbuf[rk][sub * 8] =
                    *(const uint4*)(hl16 + (size_t)src[rk] * DO + sub * 8);
        }
    }
    __syncthreads();

    const int wid = t >> 6, lane = t & 63;
    {
        const float4 hr4 = *(const float4*)(hr + (size_t)i * DO + lane * 4);
        const float4 at4 = *(const float4*)(att + lane * 4);
#pragma unroll 1
        for (int k = wid; k < NSRC; k += 4) {
            const __half2 h01 = *(const __half2*)&hbuf[k][lane * 4];
            const __half2 h23 = *(const __half2*)&hbuf[k][lane * 4 + 2];
            const float2 f01 = __half22float2(h01);
            const float2 f23 = __half22float2(h23);
            float z, p = 0.f;
            z = f01.x + hr4.x; p = fmaf(z > 0.f ? z : NEG * z, at4.x, p);
            z = f01.y + hr4.y; p = fmaf(z > 0.f ? z : NEG * z, at4.y, p);
            z = f23.x + hr4.z; p = fmaf(z > 0.f ? z : NEG * z, at4.z, p);
            z = f23.y + hr4.w; p = fmaf(z > 0.f ? z : NEG * z, at4.w, p);
#pragma unroll
            for (int off = 32; off >= 1; off >>= 1) p += __shfl_xor(p, off);
            if (lane == 0) eS[k] = p;
        }
    }
    __syncthreads();
    if (wid == 0) {
        const float v = (lane < NSRC) ? eS[lane] : -3.4e38f;
        float m = v;
#pragma unroll
        for (int off = 32; off >= 1; off >>= 1) m = fmaxf(m, __shfl_xor(m, off));
        float w = (lane < NSRC) ? __expf(v - m) : 0.f;
        float s = w;
#pragma unroll
        for (int off = 32; off >= 1; off >>= 1) s += __shfl_xor(s, off);
        if (lane < NSRC) alphaS[lane] = w / s;
    }
    __syncthreads();
    float o = bias[t];
#pragma unroll
    for (int k = 0; k < NSRC; ++k)
        o = fmaf(alphaS[k], __half2float(hbuf[k][t]), o);
    out[(size_t)i * DO + t] = o;
}

extern "C" void kernel_launch(void* const* d_in, const int* in_sizes, int n_in,
                              void* d_out, int out_size, void* d_ws, size_t ws_size,
                              hipStream_t stream) {
    const float* x    = (const float*)d_in[0];
    const float* Wl   = (const float*)d_in[1];
    const float* bl   = (const float*)d_in[2];
    const float* Wr   = (const float*)d_in[3];
    const float* br   = (const float*)d_in[4];
    const float* att  = (const float*)d_in[5];
    const float* bias = (const float*)d_in[6];
    float* out = (float*)d_out;

    char* ws = (char*)d_ws;
    // layout (bytes); hl16/hr alias cand (cand fully consumed by
    // rerank_select_k before hgemm_k writes them — stream-ordered):
    unsigned short* Bh  = (unsigned short*)(ws + 0);          //  2,621,440
    double* sq64 = (double*)(ws + 2621440);                   //     80,128
    float*  sq32 = (float*)(ws + 2701568);                    //     40,960
    unsigned* Trow = (unsigned*)(ws + 2742528);               //     40,064
    int*    nbr  = (int*)(ws + 2782592);                      //  1,280,000
    unsigned* cand = (unsigned*)(ws + 4062592);               // 51,281,920
    __half* hl16 = (__half*)(ws + 4062592);                   //  5,120,000 (alias)
    float*  hr   = (float*)(ws + 9182592);                    // 10,240,000 (alias)
    // total = 55,344,512 bytes

    prep_k<<<dim3(NTILE), 256, 0, stream>>>(x, Bh, sq64, sq32);
    thresh_k<<<dim3(ATILE), 256, 0, stream>>>(Bh, sq32, Trow);
    knn_emit_k<<<dim3(ATILE / 2, NCB), 256, 0, stream>>>(Bh, sq32, Trow, cand);
    rerank_select_k<<<dim3(NN), 64, 0, stream>>>(x, sq64, cand, nbr);
    hgemm_k<<<dim3(NN / RB), 256, 0, stream>>>(x, Wl, bl, Wr, br, hl16, hr);
    gat_k<<<dim3(NN), 256, 0, stream>>>(hl16, hr, nbr, att, bias, out);
}

// Round 13
// 259.425 us; speedup vs baseline: 2.3201x; 1.0274x over previous
//
#include <hip/hip_runtime.h>
#include <hip/hip_fp16.h>

#define NN     10000
#define DI     128
#define DO     256
#define KNB    32
#define NSRC   33      // 32 neighbors + self
#define RB     16
#define NP2    10240
#define NTILE  640     // NP2/16 tiles (B side; A reuses these fragments)
#define ATILE  626     // row tiles (covers 10016 rows, pad zeroed)
#define NCB    20      // col blocks of 512
#define SEG    64      // per-(row,colblock) LDS staging capacity
#define CAP    1024    // per-row compact capacity (count ~312 +- 77 -> 9 sigma)
#define NEG    0.2f

typedef __attribute__((ext_vector_type(8))) short bf16x8;
typedef __attribute__((ext_vector_type(4))) float f32x4;

// monotone map f32 -> u32 preserving < order (handles negatives)
__device__ __forceinline__ unsigned fkey(float f) {
    unsigned u = __float_as_uint(f);
    return (u & 0x80000000u) ? ~u : (u | 0x80000000u);
}
__device__ __forceinline__ unsigned short bf16rne(float f) {
    unsigned u = __float_as_uint(f);
    unsigned r = u + 0x7FFFu + ((u >> 16) & 1u);
    return (unsigned short)(r >> 16);
}

// Fused prep: stage 16 rows of x, emit bf16(hi) MFMA fragments (shared by the
// A and B operands — identical lane layout), f64/f32 squared norms.
__global__ __launch_bounds__(256) void prep_k(const float* __restrict__ x,
    unsigned short* __restrict__ Bh, double* __restrict__ sq64,
    float* __restrict__ sq32)
{
    __shared__ float xs[16][132];   // +4 pad: conflict-free strided reads
    const int t = threadIdx.x;
    const int tile = blockIdx.x;
    const int i0 = tile * 16;
#pragma unroll
    for (int q = 0; q < 2; ++q) {
        const int idx = t + 256 * q;
        const int r = idx >> 5, c4 = idx & 31;
        float4 v = make_float4(0.f, 0.f, 0.f, 0.f);
        if (i0 + r < NN) v = *(const float4*)(x + (size_t)(i0 + r) * DI + c4 * 4);
        *(float4*)&xs[r][c4 * 4] = v;
    }
    __syncthreads();
    const int ks = t >> 6, flane = t & 63;
    const int srow = flane & 15;
    const int kb = ks * 32 + ((flane >> 4) & 3) * 8;
    unsigned hi2[4];
#pragma unroll
    for (int j = 0; j < 4; ++j) {
        const float v0 = xs[srow][kb + 2 * j], v1 = xs[srow][kb + 2 * j + 1];
        hi2[j] = (unsigned)bf16rne(v0) | ((unsigned)bf16rne(v1) << 16);
    }
    *(uint4*)(Bh + ((size_t)(tile * 4 + ks) * 64 + flane) * 8) =
        make_uint4(hi2[0], hi2[1], hi2[2], hi2[3]);
    const int row = t >> 4, sub = t & 15;
    double s = 0.0;
#pragma unroll
    for (int q = 0; q < 8; ++q) {
        const float v = xs[row][sub * 8 + q];
        s = fma((double)v, (double)v, s);
    }
#pragma unroll
    for (int off = 8; off >= 1; off >>= 1) s += __shfl_xor(s, off);
    if (sub == 0) {
        const int gi = i0 + row;
        sq32[gi] = (gi < NN) ? (float)s : 0.f;
        if (gi < ATILE * 16) sq64[gi] = s;
    }
}

// Per-row threshold from the chunk-0 sample: 16th-smallest u16 key of the
// row's 512 distances -> Trow raw-u32 bound (bitwise-consistent with emit).
__global__ __launch_bounds__(256) void thresh_k(
    const unsigned short* __restrict__ Bh, const float* __restrict__ sq32,
    unsigned* __restrict__ Trow)
{
    __shared__ unsigned short dist16[RB][512];
    const int rt = blockIdx.x;
    const int r0 = rt * 16;
    const int t = threadIdx.x;
    const int wid = t >> 6, lane = t & 63;
    const int wbase = wid * 128, l15 = lane & 15, rgrp = (lane >> 4) * 4;

    bf16x8 ah[4];
#pragma unroll
    for (int ks = 0; ks < 4; ++ks)
        ah[ks] = *(const bf16x8*)(Bh + ((size_t)(rt * 4 + ks) * 64 + lane) * 8);
    float sqiv[4];
#pragma unroll
    for (int rg = 0; rg < 4; ++rg) sqiv[rg] = sq32[r0 + rgrp + rg];

#pragma unroll 1
    for (int ct = 0; ct < 8; ++ct) {
        const int ctg = wid * 8 + ct;
        bf16x8 bh[4];
#pragma unroll
        for (int ks = 0; ks < 4; ++ks)
            bh[ks] = *(const bf16x8*)(Bh + ((size_t)(ctg * 4 + ks) * 64 + lane) * 8);
        f32x4 acc = {0.f, 0.f, 0.f, 0.f};
#pragma unroll
        for (int ks = 0; ks < 4; ++ks)
            acc = __builtin_amdgcn_mfma_f32_16x16x32_bf16(ah[ks], bh[ks], acc, 0, 0, 0);
        const int col = wbase + ct * 16 + l15;
        const float sqj = sq32[col];
#pragma unroll
        for (int rg = 0; rg < 4; ++rg) {
            const int row = r0 + rgrp + rg;
            const float dd = __builtin_fmaf(-2.f, acc[rg], sqiv[rg] + sqj);
            unsigned k16 = (__float_as_uint(dd) >> 16) | 0x8000u;
            if (col >= NN || col == row) k16 = 0xFFFFu;
            dist16[rgrp + rg][col] = (unsigned short)k16;
        }
    }
    __syncthreads();

#pragma unroll 1
    for (int rr = 0; rr < 4; ++rr) {
        const int r = wid * 4 + rr;
        unsigned kk[8];
#pragma unroll
        for (int u = 0; u < 8; ++u) kk[u] = dist16[r][lane + 64 * u];
        unsigned lo = 0, hi = 0xFFFFu;
#pragma unroll 1
        for (int it = 0; it < 16; ++it) {
            const unsigned mid = (lo + hi) >> 1;
            int c2 = 0;
#pragma unroll
            for (int u = 0; u < 8; ++u)
                c2 += (int)__popcll(__ballot(kk[u] <= mid));
            if (c2 >= 16) hi = mid; else lo = mid;
        }
        if (lane == 0) Trow[r0 + r] = ((hi & 0x7FFFu) << 16) | 0xFFFFu;
    }
}

// Main pass: 32 rows x 512 cols per block, hi-only MFMA distances, threshold
// compare, per-lane LDS-atomic append; epilogue reserves a per-row range in
// the compact list (one global atomic per row per block) and copies only the
// real candidates.
__global__ __launch_bounds__(256) void knn_emit_k(
    const unsigned short* __restrict__ Bh, const float* __restrict__ sq32,
    const unsigned* __restrict__ Trow, unsigned* __restrict__ cnt,
    unsigned* __restrict__ cand)
{
    __shared__ unsigned lcnt[32];
    __shared__ unsigned basebuf[32];
    __shared__ unsigned cbuf[32][SEG];   // 8 KB
    const int r0 = blockIdx.x * 32;
    const int cbase = blockIdx.y * 512;
    const int t = threadIdx.x;
    const int wid = t >> 6, lane = t & 63;
    const int wbase = wid * 128, l15 = lane & 15, rgrp = (lane >> 4) * 4;
    if (t < 32) lcnt[t] = 0;

    bf16x8 ah[2][4];
#pragma unroll
    for (int rt2 = 0; rt2 < 2; ++rt2)
#pragma unroll
        for (int ks = 0; ks < 4; ++ks) {
            const int rt = (r0 >> 4) + rt2;
            ah[rt2][ks] = *(const bf16x8*)(Bh + ((size_t)(rt * 4 + ks) * 64 + lane) * 8);
        }
    float sqiv[2][4];
    unsigned TUv[2][4];
#pragma unroll
    for (int rt2 = 0; rt2 < 2; ++rt2)
#pragma unroll
        for (int rg = 0; rg < 4; ++rg) {
            const int row = r0 + rt2 * 16 + rgrp + rg;
            sqiv[rt2][rg] = sq32[row];
            TUv[rt2][rg] = Trow[row];
        }
    float sqjv[8];
#pragma unroll
    for (int ct = 0; ct < 8; ++ct)
        sqjv[ct] = sq32[cbase + wbase + ct * 16 + l15];
    __syncthreads();

    const int ctg0 = (cbase >> 4) + wid * 8;
    bf16x8 bh[4];
#pragma unroll
    for (int ks = 0; ks < 4; ++ks)
        bh[ks] = *(const bf16x8*)(Bh + ((size_t)(ctg0 * 4 + ks) * 64 + lane) * 8);

#pragma unroll 1
    for (int ct = 0; ct < 8; ++ct) {
        bf16x8 bhn[4];
        if (ct < 7) {
#pragma unroll
            for (int ks = 0; ks < 4; ++ks)
                bhn[ks] = *(const bf16x8*)(Bh + ((size_t)((ctg0 + ct + 1) * 4 + ks) * 64 + lane) * 8);
        }
        f32x4 a0 = {0.f, 0.f, 0.f, 0.f}, a1 = {0.f, 0.f, 0.f, 0.f};
#pragma unroll
        for (int ks = 0; ks < 4; ++ks) {
            a0 = __builtin_amdgcn_mfma_f32_16x16x32_bf16(ah[0][ks], bh[ks], a0, 0, 0, 0);
            a1 = __builtin_amdgcn_mfma_f32_16x16x32_bf16(ah[1][ks], bh[ks], a1, 0, 0, 0);
        }
        const int col = cbase + wbase + ct * 16 + l15;
        const float sqj = sqjv[ct];
#pragma unroll
        for (int rt2 = 0; rt2 < 2; ++rt2)
#pragma unroll
            for (int rg = 0; rg < 4; ++rg) {
                const int lrow = rt2 * 16 + rgrp + rg;
                const float dd = __builtin_fmaf(-2.f, (rt2 ? a1 : a0)[rg],
                                                sqiv[rt2][rg] + sqj);
                const unsigned raw = __float_as_uint(dd);
                if ((raw <= TUv[rt2][rg]) && (col < NN) && (col != r0 + lrow)) {
                    const unsigned slot = atomicAdd(&lcnt[lrow], 1u);
                    if (slot < SEG)
                        cbuf[lrow][slot] =
                            (((raw >> 16) | 0x8000u) << 16) | (unsigned)col;
                }
            }
#pragma unroll
        for (int ks = 0; ks < 4; ++ks) bh[ks] = bhn[ks];
    }

    __syncthreads();
    if (t < 32) {
        unsigned c = lcnt[t]; if (c > SEG) c = SEG;
        lcnt[t] = c;
        basebuf[t] = atomicAdd(&cnt[r0 + t], c);   // one atomic per row per block
    }
    __syncthreads();
#pragma unroll
    for (int q = 0; q < (32 * SEG) / 256; ++q) {
        const int idx = t + 256 * q;
        const int lr = idx >> 6, sl = idx & 63;
        if ((unsigned)sl < lcnt[lr]) {
            const unsigned b = basebuf[lr] + (unsigned)sl;
            if (b < CAP) cand[(size_t)(r0 + lr) * CAP + b] = cbuf[lr][sl];
        }
    }
}

// Per row (256 threads): wave 0 bisects top-64 of the compact list; 4 lanes
// per candidate compute the exact f64 re-rank dot; wave 0 rank-scatters the
// final top-32 in (f32-dist, col) order.
__global__ __launch_bounds__(256) void rerank_select_k(
    const float* __restrict__ x, const double* __restrict__ sq64,
    const unsigned* __restrict__ cand, const unsigned* __restrict__ cnt,
    int* __restrict__ nbr)
{
    __shared__ unsigned cbuf[64];
    __shared__ float xrs[DI];
    __shared__ unsigned long long kbuf[64];
    const int i = blockIdx.x, t = threadIdx.x;
    const int lane = t & 63;

    if (t >= 64 && t < 96)   // wave 1: stage x_row (512 B)
        *(float4*)&xrs[(t - 64) * 4] = *(const float4*)(x + (size_t)i * DI + (t - 64) * 4);

    if (t < 64) {            // wave 0: top-64 select
        cbuf[lane] = 0xFFFFFFFFu;
        unsigned n = cnt[i]; if (n > CAP) n = CAP;
        unsigned kk[CAP / 64];   // 16
#pragma unroll
        for (int u = 0; u < CAP / 64; ++u) {
            const unsigned idx = (unsigned)lane + 64u * u;
            kk[u] = (idx < n) ? cand[(size_t)i * CAP + idx] : 0xFFFFFFFFu;
        }
        unsigned lo = 0, hi = 0xFFFFFFFFu;
#pragma unroll 1
        for (int it = 0; it < 32; ++it) {
            const unsigned mid = lo + ((hi - lo) >> 1);
            int c2 = 0;
#pragma unroll
            for (int u = 0; u < CAP / 64; ++u)
                c2 += (int)__popcll(__ballot(kk[u] <= mid));
            if (c2 >= 64) hi = mid; else lo = mid;
        }
        const unsigned T = hi;
        const unsigned long long lml = (1ull << lane) - 1;
        unsigned pref = 0;
#pragma unroll
        for (int u = 0; u < CAP / 64; ++u) {
            const unsigned long long b = __ballot(kk[u] <= T);
            const int slot = (int)pref + (int)__popcll(b & lml);
            if (kk[u] <= T && slot < 64) cbuf[slot] = kk[u];
            pref += (unsigned)__popcll(b);
        }
    }
    __syncthreads();

    // 4 lanes per candidate: f64 dot via float4 loads
    const unsigned c32 = cbuf[t >> 2];
    const int col = (int)(c32 & 0xFFFFu);
    const bool valid = (col < NN);
    const int sc = valid ? col : 0;
    const int sub = t & 3;
    double a = 0.0;
    const float* xc = x + (size_t)sc * DI + sub * 32;
    const float* xr = &xrs[sub * 32];
#pragma unroll
    for (int q = 0; q < 8; ++q) {
        const float4 v = *(const float4*)(xc + q * 4);
        const float4 r = *(const float4*)(xr + q * 4);
        a = fma((double)r.x, (double)v.x, a);
        a = fma((double)r.y, (double)v.y, a);
        a = fma((double)r.z, (double)v.z, a);
        a = fma((double)r.w, (double)v.w, a);
    }
    a += __shfl_xor(a, 1);
    a += __shfl_xor(a, 2);
    if (sub == 0) {
        const float dd = (float)(sq64[i] + sq64[sc] - 2.0 * a);
        kbuf[t >> 2] = valid
            ? (((unsigned long long)fkey(dd) << 32) | (unsigned)col) : ~0ull;
    }
    __syncthreads();

    if (t < 64) {   // wave 0: rank & scatter
        const unsigned long long key = kbuf[lane];
        int rank = 0;
#pragma unroll 1
        for (int l = 0; l < 64; ++l) {
            const unsigned long long kl = __shfl(key, l);
            rank += (kl < key) ? 1 : 0;
        }
        if (key != ~0ull && rank < KNB) nbr[(size_t)i * KNB + rank] = (int)(key & 0xFFFFu);
    }
}

// h_l = x@W_l + b_l (fp16 out, for gat gather); h_r = x@W_r + b_r (f32)
__global__ __launch_bounds__(256) void hgemm_k(
    const float* __restrict__ x, const float* __restrict__ Wl,
    const float* __restrict__ bl, const float* __restrict__ Wr,
    const float* __restrict__ br, __half* __restrict__ hl16, float* __restrict__ hr)
{
    const int c = threadIdx.x;
    const int r0 = blockIdx.x * RB;
    float accl[RB], accr[RB];
    const float blv = bl[c], brv = br[c];
#pragma unroll
    for (int r = 0; r < RB; ++r) { accl[r] = blv; accr[r] = brv; }
    for (int d = 0; d < DI; ++d) {
        const float wl = Wl[d * DO + c];
        const float wr = Wr[d * DO + c];
#pragma unroll
        for (int r = 0; r < RB; ++r) {
            const float xv = x[(size_t)(r0 + r) * DI + d];  // wave-uniform
            accl[r] = fmaf(xv, wl, accl[r]);
            accr[r] = fmaf(xv, wr, accr[r]);
        }
    }
#pragma unroll
    for (int r = 0; r < RB; ++r) {
        hl16[(size_t)(r0 + r) * DO + c] = __float2half(accl[r]);
        hr[(size_t)(r0 + r) * DO + c] = accr[r];
    }
}

// attention epilogue: block=row. Stage all 33 hl16 rows in LDS once;
// e-phase: wave w owns k in {w, w+4, ...} (4 dims/lane, intra-wave reduce);
// softmax on wave 0; output phase reads LDS (2-way bank alias = free).
__global__ __launch_bounds__(256) void gat_k(
    const __half* __restrict__ hl16, const float* __restrict__ hr,
    const int* __restrict__ nbr, const float* __restrict__ att,
    const float* __restrict__ bias, float* __restrict__ out)
{
    __shared__ int src[NSRC];
    __shared__ __align__(16) __half hbuf[NSRC][DO];   // 16,896 B
    __shared__ float eS[NSRC];
    __shared__ float alphaS[NSRC];
    const int i = blockIdx.x, t = threadIdx.x;
    if (t < KNB) src[t] = nbr[(size_t)i * KNB + t];
    if (t == KNB) src[KNB] = i;   // self-loop appended last
    __syncthreads();

    {   // stage 33 rows: 32 threads x 16B per row
        const int sub = t & 31, rb = t >> 5;
#pragma unroll
        for (int s = 0; s < 5; ++s) {
            const int rk = s * 8 + rb;
            if (rk < NSRC)
                *(uint4*)&hbuf[rk][sub * 8] =
                    *(const uint4*)(hl16 + (size_t)src[rk] * DO + sub * 8);
        }
    }
    __syncthreads();

    const int wid = t >> 6, lane = t & 63;
    {
        const float4 hr4 = *(const float4*)(hr + (size_t)i * DO + lane * 4);
        const float4 at4 = *(const float4*)(att + lane * 4);
#pragma unroll 1
        for (int k = wid; k < NSRC; k += 4) {
            const __half2 h01 = *(const __half2*)&hbuf[k][lane * 4];
            const __half2 h23 = *(const __half2*)&hbuf[k][lane * 4 + 2];
            const float2 f01 = __half22float2(h01);
            const float2 f23 = __half22float2(h23);
            float z, p = 0.f;
            z = f01.x + hr4.x; p = fmaf(z > 0.f ? z : NEG * z, at4.x, p);
            z = f01.y + hr4.y; p = fmaf(z > 0.f ? z : NEG * z, at4.y, p);
            z = f23.x + hr4.z; p = fmaf(z > 0.f ? z : NEG * z, at4.z, p);
            z = f23.y + hr4.w; p = fmaf(z > 0.f ? z : NEG * z, at4.w, p);
#pragma unroll
            for (int off = 32; off >= 1; off >>= 1) p += __shfl_xor(p, off);
            if (lane == 0) eS[k] = p;
        }
    }
    __syncthreads();
    if (wid == 0) {
        const float v = (lane < NSRC) ? eS[lane] : -3.4e38f;
        float m = v;
#pragma unroll
        for (int off = 32; off >= 1; off >>= 1) m = fmaxf(m, __shfl_xor(m, off));
        float w = (lane < NSRC) ? __expf(v - m) : 0.f;
        float s = w;
#pragma unroll
        for (int off = 32; off >= 1; off >>= 1) s += __shfl_xor(s, off);
        if (lane < NSRC) alphaS[lane] = w / s;
    }
    __syncthreads();
    float o = bias[t];
#pragma unroll
    for (int k = 0; k < NSRC; ++k)
        o = fmaf(alphaS[k], __half2float(hbuf[k][t]), o);
    out[(size_t)i * DO + t] = o;
}

extern "C" void kernel_launch(void* const* d_in, const int* in_sizes, int n_in,
                              void* d_out, int out_size, void* d_ws, size_t ws_size,
                              hipStream_t stream) {
    const float* x    = (const float*)d_in[0];
    const float* Wl   = (const float*)d_in[1];
    const float* bl   = (const float*)d_in[2];
    const float* Wr   = (const float*)d_in[3];
    const float* br   = (const float*)d_in[4];
    const float* att  = (const float*)d_in[5];
    const float* bias = (const float*)d_in[6];
    float* out = (float*)d_out;

    char* ws = (char*)d_ws;
    // layout (bytes); hl16/hr alias cand (cand fully consumed by
    // rerank_select_k before hgemm_k writes them — stream-ordered):
    unsigned short* Bh  = (unsigned short*)(ws + 0);          //  2,621,440
    double* sq64 = (double*)(ws + 2621440);                   //     80,128
    float*  sq32 = (float*)(ws + 2701568);                    //     40,960
    unsigned* Trow = (unsigned*)(ws + 2742528);               //     40,064
    unsigned* cnt  = (unsigned*)(ws + 2782592);               //     40,064
    int*    nbr  = (int*)(ws + 2822656);                      //  1,280,000
    unsigned* cand = (unsigned*)(ws + 4102656);               // 41,025,536
    __half* hl16 = (__half*)(ws + 4102656);                   //  5,120,000 (alias)
    float*  hr   = (float*)(ws + 9222656);                    // 10,240,000 (alias)
    // total = 45,128,192 bytes

    hipMemsetAsync(cnt, 0, ATILE * 16 * sizeof(unsigned), stream);
    prep_k<<<dim3(NTILE), 256, 0, stream>>>(x, Bh, sq64, sq32);
    thresh_k<<<dim3(ATILE), 256, 0, stream>>>(Bh, sq32, Trow);
    knn_emit_k<<<dim3(ATILE / 2, NCB), 256, 0, stream>>>(Bh, sq32, Trow, cnt, cand);
    rerank_select_k<<<dim3(NN), 256, 0, stream>>>(x, sq64, cand, cnt, nbr);
    hgemm_k<<<dim3(NN / RB), 256, 0, stream>>>(x, Wl, bl, Wr, br, hl16, hr);
    gat_k<<<dim3(NN), 256, 0, stream>>>(hl16, hr, nbr, att, bias, out);
}